// Round 10
// baseline (371.558 us; speedup 1.0000x reference)
//
#include <hip/hip_runtime.h>
#include <hip/hip_fp16.h>
#include <hip/hip_cooperative_groups.h>

namespace cg = cooperative_groups;

#define BATCH 64
#define KSLOT 64
#define DDIM  128
#define HDIM  128
#define TTYPE 4
#define NSLOT (BATCH*KSLOT)
#define EPSLN 1e-5f
#define YROW  544   // 4*128 y + 4 wsum + 28 pad (pad zeroed by pair phase)

typedef _Float16 v8h __attribute__((ext_vector_type(8)));
typedef _Float16 v4h __attribute__((ext_vector_type(4)));
typedef _Float16 v2h __attribute__((ext_vector_type(2)));
typedef float    v4f __attribute__((ext_vector_type(4)));

__device__ __forceinline__ float waveAllSum(float v) {
    #pragma unroll
    for (int m = 1; m < 64; m <<= 1) v += __shfl_xor(v, m, 64);
    return v;
}

#define LROW 136

__device__ __forceinline__ void cluster4(v4f& p0, v4f& p1, v4f& p2, v4f& p3,
                                         const v8h x[4], const v8h bf[4][4],
                                         const v4f bias[4]) {
    p0 = bias[0]; p1 = bias[1]; p2 = bias[2]; p3 = bias[3];
    #pragma unroll
    for (int ks = 0; ks < 4; ks++) {
        p0 = __builtin_amdgcn_mfma_f32_16x16x32_f16(x[ks], bf[0][ks], p0, 0, 0, 0);
        p1 = __builtin_amdgcn_mfma_f32_16x16x32_f16(x[ks], bf[1][ks], p1, 0, 0, 0);
        p2 = __builtin_amdgcn_mfma_f32_16x16x32_f16(x[ks], bf[2][ks], p2, 0, 0, 0);
        p3 = __builtin_amdgcn_mfma_f32_16x16x32_f16(x[ks], bf[3][ks], p3, 0, 0, 0);
    }
}

__device__ __forceinline__ void epi4(v4h yacch[4], v4h& wsacch,
                                     const v4f& p0, const v4f& p1,
                                     const v4f& p2, const v4f& p3, v4h wv) {
    const v4h zero4h = {0,0,0,0};
    #define EPI1(P, OT) { \
        v2h lo = __builtin_bit_cast(v2h, __builtin_amdgcn_cvt_pkrtz(P[0], P[1])); \
        v2h hi = __builtin_bit_cast(v2h, __builtin_amdgcn_cvt_pkrtz(P[2], P[3])); \
        v4h rel = {lo[0], lo[1], hi[0], hi[1]}; \
        rel = __builtin_elementwise_max(rel, zero4h); \
        yacch[OT] = yacch[OT] + wv * rel; }
    EPI1(p0, 0) EPI1(p1, 1) EPI1(p2, 2) EPI1(p3, 3)
    #undef EPI1
    wsacch = wsacch + wv;
}

// ---------- k_fused: wconv + 2x(pair + mega) in one cooperative launch ----------
// 256 blocks x 512 threads, 1 block/CU (95232 B LDS). grid.sync() x4 replaces
// 4 kernel boundaries. Phase math is byte-identical to R8's kernels.
extern "C" __global__ __launch_bounds__(512, 2) void k_fused(
        const float* __restrict__ slots, const float* __restrict__ ep,
        const float* __restrict__ et,
        const float* __restrict__ ls_g, const float* __restrict__ ls_b,
        const float* __restrict__ ws1, const float* __restrict__ bs1,
        const float* __restrict__ ws2, const float* __restrict__ bs2,
        const float* __restrict__ wi1, const float* __restrict__ bi1,
        const float* __restrict__ wi2, const float* __restrict__ bi2,
        const float* __restrict__ wi3, const float* __restrict__ bi3,
        const float* __restrict__ lu_g, const float* __restrict__ lu_b,
        const float* __restrict__ wu1, const float* __restrict__ bu1,
        const float* __restrict__ wu2, const float* __restrict__ bu2,
        float* __restrict__ out, float* __restrict__ h_buf,
        __half* __restrict__ Ycat, __half* __restrict__ wPre,
        __half* __restrict__ ws1T, __half* __restrict__ wi1catT,
        __half* __restrict__ ws2T, __half* __restrict__ wu1T,
        __half* __restrict__ wu2T, __half* __restrict__ w3catT,
        __half* __restrict__ w2T16, float* __restrict__ biascat) {
    __shared__ __align__(16) char smem[95232];
    cg::grid_group grid = cg::this_grid();
    int bx = blockIdx.x, tid = threadIdx.x;

    // ================= phase W: weight transpose/convert + wPre =================
    {
        int b2 = bx >> 2, chunk = bx & 3;
        const float4* etb = (const float4*)(et + (size_t)b2*16384);
        const float*  epb = ep + (size_t)b2*4096;
        __half* wp0 = wPre + ((size_t)0*BATCH + b2)*4096;
        __half* wp1 = wPre + ((size_t)1*BATCH + b2)*4096;
        __half* wp2 = wPre + ((size_t)2*BATCH + b2)*4096;
        __half* wp3 = wPre + ((size_t)3*BATCH + b2)*4096;
        int c0 = chunk*1024;
        for (int c = c0 + tid; c < c0 + 1024; c += 512) {
            float wv = epb[c];
            float4 e = etb[c];
            wp0[c] = __float2half(wv * e.x);
            wp1[c] = __float2half(wv * e.y);
            wp2[c] = __float2half(wv * e.z);
            wp3[c] = __float2half(wv * e.w);
        }
        if (bx < 21) {
            const float* src; __half* dst; int dstride = 128, dcol = 0;
            if (bx == 0)      { src = ws1; dst = ws1T; }
            else if (bx <= 8) { int th = bx-1, tu = th>>1, half = th&1;
                                src = wi1 + ((size_t)tu*256 + half*128)*128;
                                dst = wi1catT + (size_t)th*128*128; }
            else if (bx == 9) { src = ws2; dst = ws2T; }
            else if (bx ==10) { src = wu2; dst = wu2T; }
            else if (bx <=12) { int hh = bx-11; src = wu1 + (size_t)hh*128*128;
                                dst = wu1T; dstride = 256; dcol = hh*128; }
            else if (bx <=16) { int tu = bx-13; src = wi3 + (size_t)tu*16384;
                                dst = w3catT; dstride = YROW; dcol = tu*128; }
            else              { int tu = bx-17; src = wi2 + (size_t)tu*16384;
                                dst = w2T16 + (size_t)tu*16384; }
            float* tile = (float*)smem;   // 128*132*4 = 67584 B
            for (int idx = tid; idx < 4096; idx += 512) {
                int r = idx >> 5, c4 = idx & 31;
                *(float4*)&tile[r*132 + c4*4] = *(const float4*)&src[(size_t)r*128 + c4*4];
            }
            __syncthreads();
            for (int idx = tid; idx < 8192; idx += 512) {
                int nn = idx >> 6, kp = idx & 63;
                __half2 pq = __floats2half2_rn(tile[(2*kp)*132 + nn], tile[(2*kp+1)*132 + nn]);
                *(__half2*)&dst[(size_t)nn*dstride + dcol + 2*kp] = pq;
            }
        } else if (bx == 21) {
            for (int idx = tid; idx < 128*32; idx += 512) {
                int o = idx >> 5, c = idx & 31;
                w3catT[(size_t)o*YROW + 512 + c] = (c < 4) ? __float2half(bi3[c*DDIM + o]) : __float2half(0.f);
            }
            for (int idx = tid; idx < 1024; idx += 512) {
                int th = idx >> 7, o = idx & 127;
                biascat[idx] = (th & 1) ? bi1[(th>>1)*HDIM + o] : 0.f;
            }
        }
    }
    grid.sync();

    for (int mp = 0; mp < 2; mp++) {
        const float* hin = (mp == 0) ? slots : h_buf;
        float* hout = (mp == 0) ? h_buf : out;

        // ================= phase P: pair (R8 k_pair body) =================
        {
            _Float16* w2T = (_Float16*)smem;      // 17408 halves
            _Float16* Cs  = w2T + 17408;          //  8704
            _Float16* As  = Cs  + 8704;           //  8704
            _Float16* wS  = As  + 8704;           //  4096
            _Float16* hs  = wS  + 4096;           //  8704  -> 95232 B
            int b = bx >> 2, tau = bx & 3;
            int lane = tid & 63, w = tid >> 6;
            int jt = w >> 1, oh = w & 1, quad = lane >> 4, n = lane & 15;

            for (int idx = tid; idx < 2048; idx += 512) {
                int o = idx >> 4, seg = (idx & 15)*8;
                *(v8h*)&w2T[o*LROW + seg] = *(const v8h*)&w2T16[((size_t)tau*128 + o)*128 + seg];
            }
            {
                int row = tid >> 3, c0 = (tid & 7)*16;
                const float* hp = &hin[(size_t)(b*KSLOT + row)*128 + c0];
                #pragma unroll
                for (int q = 0; q < 4; q++) {
                    float4 f = *(const float4*)&hp[q*4];
                    *(__half2*)&hs[row*136 + c0 + q*4]     = __floats2half2_rn(f.x, f.y);
                    *(__half2*)&hs[row*136 + c0 + q*4 + 2] = __floats2half2_rn(f.z, f.w);
                }
            }
            {
                int base = tid*8;
                *(v8h*)&wS[base] = *(const v8h*)&wPre[((size_t)tau*BATCH + b)*4096 + base];
            }
            __syncthreads();

            // phase 1: As/Cs = hs @ wi1[tau] (+bias on C)
            {
                int hf = w >> 2, rt = w & 3;
                const __half* wb = wi1catT + (size_t)(tau*2 + hf)*128*128;
                const float* bcp = biascat + (tau*2 + hf)*128;
                _Float16* dst = hf ? Cs : As;
                v8h afr[4];
                #pragma unroll
                for (int ks = 0; ks < 4; ks++)
                    afr[ks] = *(const v8h*)&hs[(rt*16 + n)*136 + ks*32 + quad*8];
                #pragma unroll
                for (int ot = 0; ot < 8; ot++) {
                    float b0 = bcp[ot*16 + n];
                    v4f acc = (v4f){b0, b0, b0, b0};
                    #pragma unroll
                    for (int ks = 0; ks < 4; ks++)
                        acc = __builtin_amdgcn_mfma_f32_16x16x32_f16(
                            afr[ks], *(const v8h*)&wb[(size_t)(ot*16 + n)*128 + ks*32 + quad*8], acc, 0, 0, 0);
                    #pragma unroll
                    for (int r = 0; r < 4; r++)
                        dst[(rt*16 + quad*4 + r)*LROW + ot*16 + n] = (_Float16)acc[r];
                }
            }
            __syncthreads();

            // phase 2: i-loop, 2-wide pipelined
            v8h bfrag[4][4];
            #pragma unroll
            for (int ot = 0; ot < 4; ot++)
                #pragma unroll
                for (int ks = 0; ks < 4; ks++)
                    bfrag[ot][ks] = *(const v8h*)&w2T[(oh*64 + ot*16 + n)*LROW + ks*32 + quad*8];
            v8h cfrag[4];
            #pragma unroll
            for (int ks = 0; ks < 4; ks++)
                cfrag[ks] = *(const v8h*)&Cs[(jt*16 + n)*LROW + ks*32 + quad*8];
            v4f biasvec[4];
            #pragma unroll
            for (int ot = 0; ot < 4; ot++) {
                float b0 = bi2[tau*HDIM + oh*64 + ot*16 + n];
                biasvec[ot] = (v4f){b0, b0, b0, b0};
            }

            v4h yacch[4];
            #pragma unroll
            for (int ot = 0; ot < 4; ot++) yacch[ot] = (v4h){0,0,0,0};
            v4h wsacch = (v4h){0,0,0,0};
            const v8h zero8 = {0,0,0,0,0,0,0,0};

            #define LOADA(DST, WV, I) { int _i = (I); \
                DST[0] = *(const v8h*)&As[_i*LROW +  0 + quad*8]; \
                DST[1] = *(const v8h*)&As[_i*LROW + 32 + quad*8]; \
                DST[2] = *(const v8h*)&As[_i*LROW + 64 + quad*8]; \
                DST[3] = *(const v8h*)&As[_i*LROW + 96 + quad*8]; \
                WV = *(const v4h*)&wS[_i*KSLOT + jt*16 + quad*4]; }

            v8h aA[4], aB[4], xA[4], xB[4];
            v4h wvA, wvB, wvEA, wvEB;
            LOADA(aA, wvA, 0)
            LOADA(aB, wvB, 1)
            #pragma unroll
            for (int ks = 0; ks < 4; ks++)
                xA[ks] = __builtin_elementwise_max(aA[ks] + cfrag[ks], zero8);
            v4f pA0, pA1, pA2, pA3, pB0, pB1, pB2, pB3;

            for (int ii = 0; ii < 32; ++ii) {
                int i = ii*2;
                wvEA = wvA;
                { int i2 = (i+2 < 64) ? (i+2) : 63; LOADA(aA, wvA, i2) }
                cluster4(pA0, pA1, pA2, pA3, xA, bfrag, biasvec);
                #pragma unroll
                for (int ks = 0; ks < 4; ks++)
                    xB[ks] = __builtin_elementwise_max(aB[ks] + cfrag[ks], zero8);
                epi4(yacch, wsacch, pA0, pA1, pA2, pA3, wvEA);
                wvEB = wvB;
                { int i3 = (i+3 < 64) ? (i+3) : 63; LOADA(aB, wvB, i3) }
                cluster4(pB0, pB1, pB2, pB3, xB, bfrag, biasvec);
                #pragma unroll
                for (int ks = 0; ks < 4; ks++)
                    xA[ks] = __builtin_elementwise_max(aA[ks] + cfrag[ks], zero8);
                epi4(yacch, wsacch, pB0, pB1, pB2, pB3, wvEB);
            }
            #undef LOADA

            #pragma unroll
            for (int r = 0; r < 4; r++) {
                int j = jt*16 + quad*4 + r;
                __half* yb = Ycat + (size_t)(b*KSLOT + j)*YROW + tau*128 + oh*64;
                #pragma unroll
                for (int ot = 0; ot < 4; ot++)
                    yb[ot*16 + n] = __float2half((float)yacch[ot][r]);
            }
            if (oh == 0 && n == 0) {
                #pragma unroll
                for (int r = 0; r < 4; r++)
                    Ycat[(size_t)(b*KSLOT + jt*16 + quad*4 + r)*YROW + 512 + tau] = __float2half((float)wsacch[r]);
            }
            if (tau == 0 && oh == 1 && n == 0) {
                const v4h z4 = {0,0,0,0};
                #pragma unroll
                for (int r = 0; r < 4; r++) {
                    _Float16* pz = (_Float16*)(Ycat + (size_t)(b*KSLOT + jt*16 + quad*4 + r)*YROW + 516);
                    #pragma unroll
                    for (int c = 0; c < 28; c += 4) *(v4h*)&pz[c] = z4;
                }
            }
        }
        grid.sync();

        // ================= phase M: mega (R8 k_mega v2 body, 16 rows) =================
        {
            _Float16* Ys  = (_Float16*)smem;              // 16*552 h = 17664 B
            float*    Crow = (float*)(smem + 17664);      // 16*260 f = 16640 B
            float*    Hrow = (float*)(smem + 34304);      // 16*132 f =  8448 B
            _Float16* Xs  = (_Float16*)(smem + 42752);    // 16*136 h =  4352 B
            _Float16* Ts  = (_Float16*)(smem + 47104);    // 16*136 h =  4352 B
            _Float16* Xa  = (_Float16*)(smem + 51456);    // 16*264 h =  8448 B
            _Float16* Ut  = (_Float16*)(smem + 59904);    // 16*136 h =  4352 B -> 64256
            int lane = tid & 63, w = tid >> 6;
            int n = lane & 15, quad = lane >> 4;
            int row0 = bx*16;

            for (int u = tid; u < 1024; u += 512) {
                int r = u >> 6, seg = (u & 63)*8;
                *(v8h*)&Ys[r*552 + seg] = *(const v8h*)&Ycat[(size_t)(row0 + r)*YROW + seg];
            }
            if (tid < 64) {
                int r = tid >> 2, seg = 512 + (tid & 3)*8;
                *(v8h*)&Ys[r*552 + seg] = *(const v8h*)&Ycat[(size_t)(row0 + r)*YROW + seg];
            }
            {
                int r = tid >> 5, c4 = (tid & 31)*4;
                *(float4*)&Hrow[r*132 + c4] = *(const float4*)&hin[(size_t)(row0 + r)*128 + c4];
            }
            __syncthreads();
            // dinter = Ys @ w3catT^T -> Crow[:,128:256]
            {
                const __half* wp = w3catT + (size_t)(w*16 + n)*YROW + quad*8;
                const _Float16* yp = &Ys[n*552 + quad*8];
                v4f acc = (v4f){0.f,0.f,0.f,0.f};
                #pragma unroll 4
                for (int ks = 0; ks < 17; ks++) {
                    v8h a  = *(const v8h*)(yp + ks*32);
                    v8h bf = *(const v8h*)(wp + ks*32);
                    acc = __builtin_amdgcn_mfma_f32_16x16x32_f16(a, bf, acc, 0, 0, 0);
                }
                #pragma unroll
                for (int r = 0; r < 4; r++)
                    Crow[(quad*4 + r)*260 + 128 + w*16 + n] = acc[r];
            }
            // LN(128) of h -> Xs
            #pragma unroll
            for (int rr = 0; rr < 2; rr++) {
                int r = w*2 + rr;
                float x0 = Hrow[r*132 + 2*lane], x1 = Hrow[r*132 + 2*lane + 1];
                float mu = waveAllSum(x0 + x1) * (1.f/128.f);
                float d0 = x0 - mu, d1 = x1 - mu;
                float var = waveAllSum(d0*d0 + d1*d1) * (1.f/128.f);
                float rs = rsqrtf(var + EPSLN);
                float2 gv = *(const float2*)&ls_g[2*lane];
                float2 bv = *(const float2*)&ls_b[2*lane];
                *(__half2*)&Xs[r*136 + 2*lane] = __floats2half2_rn(d0*rs*gv.x + bv.x, d1*rs*gv.y + bv.y);
            }
            __syncthreads();
            // t = relu(Xs @ ws1 + bs1)
            {
                float b0 = bs1[w*16 + n];
                v4f acc = (v4f){b0, b0, b0, b0};
                const __half* wp = ws1T + (size_t)(w*16 + n)*128 + quad*8;
                #pragma unroll
                for (int ks = 0; ks < 4; ks++) {
                    v8h a  = *(const v8h*)&Xs[n*136 + ks*32 + quad*8];
                    v8h bf = *(const v8h*)(wp + ks*32);
                    acc = __builtin_amdgcn_mfma_f32_16x16x32_f16(a, bf, acc, 0, 0, 0);
                }
                #pragma unroll
                for (int r = 0; r < 4; r++)
                    Ts[(quad*4 + r)*136 + w*16 + n] = (_Float16)fmaxf(acc[r], 0.f);
            }
            __syncthreads();
            // Crow[:,0:128] = h + t @ ws2 + bs2
            {
                float b0 = bs2[w*16 + n];
                v4f acc = (v4f){b0, b0, b0, b0};
                const __half* wp = ws2T + (size_t)(w*16 + n)*128 + quad*8;
                #pragma unroll
                for (int ks = 0; ks < 4; ks++) {
                    v8h a  = *(const v8h*)&Ts[n*136 + ks*32 + quad*8];
                    v8h bf = *(const v8h*)(wp + ks*32);
                    acc = __builtin_amdgcn_mfma_f32_16x16x32_f16(a, bf, acc, 0, 0, 0);
                }
                #pragma unroll
                for (int r = 0; r < 4; r++) {
                    int rr = quad*4 + r, col = w*16 + n;
                    Crow[rr*260 + col] = Hrow[rr*132 + col] + acc[r];
                }
            }
            __syncthreads();
            // LN(256) -> Xa
            #pragma unroll
            for (int rr = 0; rr < 2; rr++) {
                int r = w*2 + rr;
                float4 v = *(const float4*)&Crow[r*260 + 4*lane];
                float mu = waveAllSum(v.x + v.y + v.z + v.w) * (1.f/256.f);
                float d0 = v.x-mu, d1 = v.y-mu, d2 = v.z-mu, d3 = v.w-mu;
                float var = waveAllSum(d0*d0 + d1*d1 + d2*d2 + d3*d3) * (1.f/256.f);
                float rs = rsqrtf(var + EPSLN);
                float4 gv = *(const float4*)&lu_g[4*lane];
                float4 bv = *(const float4*)&lu_b[4*lane];
                *(__half2*)&Xa[r*264 + 4*lane]     = __floats2half2_rn(d0*rs*gv.x + bv.x, d1*rs*gv.y + bv.y);
                *(__half2*)&Xa[r*264 + 4*lane + 2] = __floats2half2_rn(d2*rs*gv.z + bv.z, d3*rs*gv.w + bv.w);
            }
            __syncthreads();
            // u = relu(Xa @ wu1 + bu1)
            {
                float b0 = bu1[w*16 + n];
                v4f acc = (v4f){b0, b0, b0, b0};
                const __half* wp = wu1T + (size_t)(w*16 + n)*256 + quad*8;
                const _Float16* xp = &Xa[n*264 + quad*8];
                #pragma unroll 4
                for (int ks = 0; ks < 8; ks++) {
                    v8h a  = *(const v8h*)(xp + ks*32);
                    v8h bf = *(const v8h*)(wp + ks*32);
                    acc = __builtin_amdgcn_mfma_f32_16x16x32_f16(a, bf, acc, 0, 0, 0);
                }
                #pragma unroll
                for (int r = 0; r < 4; r++)
                    Ut[(quad*4 + r)*136 + w*16 + n] = (_Float16)fmaxf(acc[r], 0.f);
            }
            __syncthreads();
            // hout = h + u @ wu2 + bu2
            {
                float b0 = bu2[w*16 + n];
                v4f acc = (v4f){b0, b0, b0, b0};
                const __half* wp = wu2T + (size_t)(w*16 + n)*128 + quad*8;
                #pragma unroll
                for (int ks = 0; ks < 4; ks++) {
                    v8h a  = *(const v8h*)&Ut[n*136 + ks*32 + quad*8];
                    v8h bf = *(const v8h*)(wp + ks*32);
                    acc = __builtin_amdgcn_mfma_f32_16x16x32_f16(a, bf, acc, 0, 0, 0);
                }
                #pragma unroll
                for (int r = 0; r < 4; r++) {
                    int rr = quad*4 + r, col = w*16 + n;
                    hout[(size_t)(row0 + rr)*128 + col] = Hrow[rr*132 + col] + acc[r];
                }
            }
        }
        if (mp == 0) grid.sync();
    }
}

// ---------- launch ----------
extern "C" void kernel_launch(void* const* d_in, const int* in_sizes, int n_in,
                              void* d_out, int out_size, void* d_ws, size_t ws_size,
                              hipStream_t stream) {
    const float* slots = (const float*)d_in[0];
    const float* ep    = (const float*)d_in[1];
    const float* et    = (const float*)d_in[2];
    const float* ls_g  = (const float*)d_in[3];
    const float* ls_b  = (const float*)d_in[4];
    const float* ws1   = (const float*)d_in[5];
    const float* bs1   = (const float*)d_in[6];
    const float* ws2   = (const float*)d_in[7];
    const float* bs2   = (const float*)d_in[8];
    const float* wi1   = (const float*)d_in[9];
    const float* bi1   = (const float*)d_in[10];
    const float* wi2   = (const float*)d_in[11];
    const float* bi2   = (const float*)d_in[12];
    const float* wi3   = (const float*)d_in[13];
    const float* bi3   = (const float*)d_in[14];
    const float* lu_g  = (const float*)d_in[15];
    const float* lu_b  = (const float*)d_in[16];
    const float* wu1   = (const float*)d_in[17];
    const float* bu1   = (const float*)d_in[18];
    const float* wu2   = (const float*)d_in[19];
    const float* bu2   = (const float*)d_in[20];
    float* out = (float*)d_out;

    char* p = (char*)d_ws;
    float*  h_buf   = (float*)p;   p += (size_t)NSLOT*DDIM*4;
    __half* Ycat    = (__half*)p;  p += (size_t)NSLOT*YROW*2;
    __half* wPre    = (__half*)p;  p += (size_t)TTYPE*BATCH*4096*2;
    __half* ws1T    = (__half*)p;  p += 128*128*2;
    __half* wi1catT = (__half*)p;  p += 1024*128*2;
    __half* ws2T    = (__half*)p;  p += 128*128*2;
    __half* wu1T    = (__half*)p;  p += 128*256*2;
    __half* wu2T    = (__half*)p;  p += 128*128*2;
    __half* w3catT  = (__half*)p;  p += 128*YROW*2;
    __half* w2T16   = (__half*)p;  p += 4*128*128*2;
    float*  biascat = (float*)p;   p += 1024*4;

    void* args[] = {
        (void*)&slots, (void*)&ep, (void*)&et, (void*)&ls_g, (void*)&ls_b,
        (void*)&ws1, (void*)&bs1, (void*)&ws2, (void*)&bs2,
        (void*)&wi1, (void*)&bi1, (void*)&wi2, (void*)&bi2, (void*)&wi3, (void*)&bi3,
        (void*)&lu_g, (void*)&lu_b, (void*)&wu1, (void*)&bu1, (void*)&wu2, (void*)&bu2,
        (void*)&out, (void*)&h_buf, (void*)&Ycat, (void*)&wPre,
        (void*)&ws1T, (void*)&wi1catT, (void*)&ws2T, (void*)&wu1T, (void*)&wu2T,
        (void*)&w3catT, (void*)&w2T16, (void*)&biascat };
    hipLaunchCooperativeKernel(reinterpret_cast<void*>(k_fused),
                               dim3(256), dim3(512), args, 0, stream);
}

// Round 11
// 223.003 us; speedup vs baseline: 1.6662x; 1.6662x over previous
//
#include <hip/hip_runtime.h>
#include <hip/hip_fp16.h>

#define BATCH 64
#define KSLOT 64
#define DDIM  128
#define HDIM  128
#define TTYPE 4
#define NSLOT (BATCH*KSLOT)
#define EPSLN 1e-5f
#define YROW  544   // 4*128 y + 4 wsum + 28 pad (pad zeroed by k_pair, killed by zero weight cols)

typedef _Float16 v8h __attribute__((ext_vector_type(8)));
typedef _Float16 v4h __attribute__((ext_vector_type(4)));
typedef _Float16 v2h __attribute__((ext_vector_type(2)));
typedef float    v4f __attribute__((ext_vector_type(4)));

__device__ __forceinline__ float waveAllSum(float v) {
    #pragma unroll
    for (int m = 1; m < 64; m <<= 1) v += __shfl_xor(v, m, 64);
    return v;
}

// ---------- k_wconv: one-time weight transpose/convert + w-precompute (R8 exact) ----------
__global__ __launch_bounds__(256) void k_wconv(
        const float* __restrict__ ws1, const float* __restrict__ wi1,
        const float* __restrict__ ws2, const float* __restrict__ wu1,
        const float* __restrict__ wu2, const float* __restrict__ wi3,
        const float* __restrict__ wi2, const float* __restrict__ bi1,
        const float* __restrict__ bi3,
        const float* __restrict__ ep, const float* __restrict__ et,
        __half* __restrict__ ws1T, __half* __restrict__ wi1catT,
        __half* __restrict__ ws2T, __half* __restrict__ wu1T,
        __half* __restrict__ wu2T, __half* __restrict__ w3catT,
        __half* __restrict__ w2T16, float* __restrict__ biascat,
        __half* __restrict__ wPre) {
    __shared__ __align__(16) float tile[128*132];
    int bx = blockIdx.x, tid = threadIdx.x;
    if (bx >= 22) {
        int bx2 = bx - 22, b = bx2 >> 2, chunk = bx2 & 3;
        const float4* etb = (const float4*)(et + (size_t)b*16384);
        const float*  epb = ep + (size_t)b*4096;
        __half* w0 = wPre + ((size_t)0*BATCH + b)*4096;
        __half* w1 = wPre + ((size_t)1*BATCH + b)*4096;
        __half* w2 = wPre + ((size_t)2*BATCH + b)*4096;
        __half* w3 = wPre + ((size_t)3*BATCH + b)*4096;
        int c0 = chunk*1024;
        for (int c = c0 + tid; c < c0 + 1024; c += 256) {
            float wv = epb[c];
            float4 e = etb[c];
            w0[c] = __float2half(wv * e.x);
            w1[c] = __float2half(wv * e.y);
            w2[c] = __float2half(wv * e.z);
            w3[c] = __float2half(wv * e.w);
        }
        return;
    }
    if (bx == 21) {
        for (int idx = tid; idx < 128*32; idx += 256) {
            int o = idx >> 5, c = idx & 31;
            w3catT[(size_t)o*YROW + 512 + c] = (c < 4) ? __float2half(bi3[c*DDIM + o]) : __float2half(0.f);
        }
        for (int idx = tid; idx < 1024; idx += 256) {
            int th = idx >> 7, o = idx & 127;
            biascat[idx] = (th & 1) ? bi1[(th>>1)*HDIM + o] : 0.f;
        }
        return;
    }
    const float* src; __half* dst; int dstride = 128, dcol = 0;
    if (bx == 0)      { src = ws1; dst = ws1T; }
    else if (bx <= 8) { int th = bx-1, tau = th>>1, half = th&1;
                        src = wi1 + ((size_t)tau*256 + half*128)*128;
                        dst = wi1catT + (size_t)th*128*128; }
    else if (bx == 9) { src = ws2; dst = ws2T; }
    else if (bx ==10) { src = wu2; dst = wu2T; }
    else if (bx <=12) { int hh = bx-11; src = wu1 + (size_t)hh*128*128;
                        dst = wu1T; dstride = 256; dcol = hh*128; }
    else if (bx <=16) { int tau = bx-13; src = wi3 + (size_t)tau*16384;
                        dst = w3catT; dstride = YROW; dcol = tau*128; }
    else              { int tau = bx-17; src = wi2 + (size_t)tau*16384;
                        dst = w2T16 + (size_t)tau*16384; }
    for (int idx = tid; idx < 4096; idx += 256) {
        int r = idx >> 5, c4 = idx & 31;
        *(float4*)&tile[r*132 + c4*4] = *(const float4*)&src[(size_t)r*128 + c4*4];
    }
    __syncthreads();
    for (int idx = tid; idx < 8192; idx += 256) {
        int n = idx >> 6, kp = idx & 63;
        __half2 p = __floats2half2_rn(tile[(2*kp)*132 + n], tile[(2*kp+1)*132 + n]);
        *(__half2*)&dst[(size_t)n*dstride + dcol + 2*kp] = p;
    }
}

// ---------- k_pair v10: low-register / 2-block-residency variant ----------
// bfrag from LDS (in-loop ds_read), hs|w2T union, (512,4) -> 64-VGPR cap (R2 regime).
// LDS: U 34816 + Cs 17408 + As 17408 + wS 8192 = 77824 B; 2x77824 <= 160K -> 2 blocks/CU.
#define LROW 136
__global__ __launch_bounds__(512, 4) void k_pair(
        const float* __restrict__ h,        // [4096][128] fp32
        const __half* __restrict__ wi1catT, // [8][128 o][128 k]
        const float* __restrict__ biascat,  // [8*128]
        const __half* __restrict__ w2T16,   // [4][128][128]
        const float* __restrict__ bi2,
        const __half* __restrict__ wPre,    // [4][64][64 i][64 j] f16
        __half* __restrict__ Ycat) {        // [4096][YROW]
    __shared__ __align__(16) _Float16 U[HDIM*LROW];     // hs (rows 0..63) then w2T (128 rows)
    __shared__ __align__(16) _Float16 Cs[KSLOT*LROW];   // 17408
    __shared__ __align__(16) _Float16 As[KSLOT*LROW];   // 17408
    __shared__ __align__(16) _Float16 wS[KSLOT*KSLOT];  //  8192 -> 77824 B
    int bx = blockIdx.x, b = bx >> 2, tau = bx & 3;
    int tid = threadIdx.x, lane = tid & 63, w = tid >> 6;
    int jt = w >> 1, oh = w & 1, quad = lane >> 4, n = lane & 15;

    // stage hs (64 rows) into U
    {
        int row = tid >> 3, c0 = (tid & 7)*16;
        const float* hp = &h[(size_t)(b*KSLOT + row)*128 + c0];
        #pragma unroll
        for (int q = 0; q < 4; q++) {
            float4 f = *(const float4*)&hp[q*4];
            *(__half2*)&U[row*LROW + c0 + q*4]     = __floats2half2_rn(f.x, f.y);
            *(__half2*)&U[row*LROW + c0 + q*4 + 2] = __floats2half2_rn(f.z, f.w);
        }
    }
    {
        int base = tid*8;
        *(v8h*)&wS[base] = *(const v8h*)&wPre[((size_t)tau*BATCH + b)*4096 + base];
    }
    __syncthreads();

    // phase 1: As/Cs = hs @ wi1[tau] (+bias on C)
    {
        int hf = w >> 2, rt = w & 3;
        const __half* wb = wi1catT + (size_t)(tau*2 + hf)*128*128;
        const float* bcp = biascat + (tau*2 + hf)*128;
        _Float16* dst = hf ? Cs : As;
        v8h afr[4];
        #pragma unroll
        for (int ks = 0; ks < 4; ks++)
            afr[ks] = *(const v8h*)&U[(rt*16 + n)*LROW + ks*32 + quad*8];
        #pragma unroll
        for (int ot = 0; ot < 8; ot++) {
            float b0 = bcp[ot*16 + n];
            v4f acc = (v4f){b0, b0, b0, b0};
            #pragma unroll
            for (int ks = 0; ks < 4; ks++)
                acc = __builtin_amdgcn_mfma_f32_16x16x32_f16(
                    afr[ks], *(const v8h*)&wb[(size_t)(ot*16 + n)*128 + ks*32 + quad*8], acc, 0, 0, 0);
            #pragma unroll
            for (int r = 0; r < 4; r++)
                dst[(rt*16 + quad*4 + r)*LROW + ot*16 + n] = (_Float16)acc[r];
        }
    }
    __syncthreads();
    // hs dead -> load w2T into U straight from global (no reg staging peak)
    #pragma unroll
    for (int k2 = 0; k2 < 4; k2++) {
        int idx = tid + k2*512;
        int o = idx >> 4, seg = (idx & 15)*8;
        *(v8h*)&U[o*LROW + seg] = *(const v8h*)&w2T16[((size_t)tau*128 + o)*128 + seg];
    }
    __syncthreads();

    // phase 2: i-loop; bfrag read from LDS per iteration (registers stay under the 64 cap)
    v8h cfrag[4];
    #pragma unroll
    for (int ks = 0; ks < 4; ks++)
        cfrag[ks] = *(const v8h*)&Cs[(jt*16 + n)*LROW + ks*32 + quad*8];
    v4f biasvec[4];
    #pragma unroll
    for (int ot = 0; ot < 4; ot++) {
        float b0 = bi2[tau*HDIM + oh*64 + ot*16 + n];
        biasvec[ot] = (v4f){b0, b0, b0, b0};
    }

    v4h yacch[4];
    #pragma unroll
    for (int ot = 0; ot < 4; ot++) yacch[ot] = (v4h){0,0,0,0};
    v4h wsacch = (v4h){0,0,0,0};
    const v8h zero8 = {0,0,0,0,0,0,0,0};
    const v4h zero4h = {0,0,0,0};

    const _Float16* ub = &U[(oh*64 + n)*LROW + quad*8];   // bfrag base; (ot,ks) are imm offsets

    for (int i = 0; i < KSLOT; ++i) {
        v8h a[4];
        #pragma unroll
        for (int ks = 0; ks < 4; ks++)
            a[ks] = *(const v8h*)&As[i*LROW + ks*32 + quad*8];
        v4h wv = *(const v4h*)&wS[i*KSLOT + jt*16 + quad*4];
        v8h x1[4];
        #pragma unroll
        for (int ks = 0; ks < 4; ks++)
            x1[ks] = __builtin_elementwise_max(a[ks] + cfrag[ks], zero8);
        v4f acc0 = biasvec[0], acc1 = biasvec[1], acc2 = biasvec[2], acc3 = biasvec[3];
        #pragma unroll
        for (int ks = 0; ks < 4; ks++) {
            acc0 = __builtin_amdgcn_mfma_f32_16x16x32_f16(x1[ks], *(const v8h*)(ub + 0*16*LROW + ks*32), acc0, 0, 0, 0);
            acc1 = __builtin_amdgcn_mfma_f32_16x16x32_f16(x1[ks], *(const v8h*)(ub + 1*16*LROW + ks*32), acc1, 0, 0, 0);
            acc2 = __builtin_amdgcn_mfma_f32_16x16x32_f16(x1[ks], *(const v8h*)(ub + 2*16*LROW + ks*32), acc2, 0, 0, 0);
            acc3 = __builtin_amdgcn_mfma_f32_16x16x32_f16(x1[ks], *(const v8h*)(ub + 3*16*LROW + ks*32), acc3, 0, 0, 0);
        }
        #define EPI(ACC, OT) { \
            v2h lo = __builtin_bit_cast(v2h, __builtin_amdgcn_cvt_pkrtz(ACC[0], ACC[1])); \
            v2h hi = __builtin_bit_cast(v2h, __builtin_amdgcn_cvt_pkrtz(ACC[2], ACC[3])); \
            v4h rel = {lo[0], lo[1], hi[0], hi[1]}; \
            rel = __builtin_elementwise_max(rel, zero4h); \
            yacch[OT] = yacch[OT] + wv * rel; }
        EPI(acc0, 0) EPI(acc1, 1) EPI(acc2, 2) EPI(acc3, 3)
        #undef EPI
        wsacch = wsacch + wv;
    }

    #pragma unroll
    for (int r = 0; r < 4; r++) {
        int j = jt*16 + quad*4 + r;
        __half* yb = Ycat + (size_t)(b*KSLOT + j)*YROW + tau*128 + oh*64;
        #pragma unroll
        for (int ot = 0; ot < 4; ot++)
            yb[ot*16 + n] = __float2half((float)yacch[ot][r]);
    }
    if (oh == 0 && n == 0) {
        #pragma unroll
        for (int r = 0; r < 4; r++)
            Ycat[(size_t)(b*KSLOT + jt*16 + quad*4 + r)*YROW + 512 + tau] = __float2half((float)wsacch[r]);
    }
    // zero pad cols 516..543 once per row (tau==0 blocks own it)
    if (tau == 0 && oh == 1 && n == 0) {
        const v4h z4 = {0,0,0,0};
        #pragma unroll
        for (int r = 0; r < 4; r++) {
            _Float16* pz = (_Float16*)(Ycat + (size_t)(b*KSLOT + jt*16 + quad*4 + r)*YROW + 516);
            #pragma unroll
            for (int c = 0; c < 28; c += 4) *(v4h*)&pz[c] = z4;
        }
    }
}

// ---------- k_mega v2 (R8 exact): B-fragments from global (L2), no weight preload ----------
__global__ __launch_bounds__(512, 2) void k_mega(
        const __half* __restrict__ Ycat, const __half* __restrict__ w3catT,
        const float* __restrict__ ls_g, const float* __restrict__ ls_b,
        const __half* __restrict__ ws1T, const float* __restrict__ bs1,
        const __half* __restrict__ ws2T, const float* __restrict__ bs2,
        const float* __restrict__ g, const float* __restrict__ bb,
        const __half* __restrict__ wu1T, const float* __restrict__ bu1,
        const __half* __restrict__ wu2T, const float* __restrict__ bu2,
        const float* __restrict__ h, float* __restrict__ hout) {
    __shared__ __align__(16) _Float16 Ys[16*552];    // 17664
    __shared__ __align__(16) float    Crow[16*260];  // 16640
    __shared__ __align__(16) float    Hrow[16*132];  //  8448
    __shared__ __align__(16) _Float16 Xs[16*136];    //  4352
    __shared__ __align__(16) _Float16 Ts[16*136];    //  4352
    __shared__ __align__(16) _Float16 Xa[16*264];    //  8448
    __shared__ __align__(16) _Float16 Ut[16*136];    //  4352  -> 64256 B
    int tid = threadIdx.x, lane = tid & 63, w = tid >> 6;
    int n = lane & 15, quad = lane >> 4;
    int row0 = blockIdx.x*16;

    for (int u = tid; u < 1024; u += 512) {
        int r = u >> 6, seg = (u & 63)*8;
        *(v8h*)&Ys[r*552 + seg] = *(const v8h*)&Ycat[(size_t)(row0 + r)*YROW + seg];
    }
    if (tid < 64) {
        int r = tid >> 2, seg = 512 + (tid & 3)*8;
        *(v8h*)&Ys[r*552 + seg] = *(const v8h*)&Ycat[(size_t)(row0 + r)*YROW + seg];
    }
    {
        int r = tid >> 5, c4 = (tid & 31)*4;
        *(float4*)&Hrow[r*132 + c4] = *(const float4*)&h[(size_t)(row0 + r)*128 + c4];
    }
    __syncthreads();
    // dinter = Ys @ w3catT^T  -> Crow[:,128:256]   (B from global, partial unroll)
    {
        const __half* wp = w3catT + (size_t)(w*16 + n)*YROW + quad*8;
        const _Float16* yp = &Ys[n*552 + quad*8];
        v4f acc = (v4f){0.f,0.f,0.f,0.f};
        #pragma unroll 4
        for (int ks = 0; ks < 17; ks++) {
            v8h a  = *(const v8h*)(yp + ks*32);
            v8h bf = *(const v8h*)(wp + ks*32);
            acc = __builtin_amdgcn_mfma_f32_16x16x32_f16(a, bf, acc, 0, 0, 0);
        }
        #pragma unroll
        for (int r = 0; r < 4; r++)
            Crow[(quad*4 + r)*260 + 128 + w*16 + n] = acc[r];
    }
    // LN(128) of h -> Xs (2 rows per wave)
    #pragma unroll
    for (int rr = 0; rr < 2; rr++) {
        int r = w*2 + rr;
        float x0 = Hrow[r*132 + 2*lane], x1 = Hrow[r*132 + 2*lane + 1];
        float mu = waveAllSum(x0 + x1) * (1.f/128.f);
        float d0 = x0 - mu, d1 = x1 - mu;
        float var = waveAllSum(d0*d0 + d1*d1) * (1.f/128.f);
        float rs = rsqrtf(var + EPSLN);
        float2 gv = *(const float2*)&ls_g[2*lane];
        float2 bv = *(const float2*)&ls_b[2*lane];
        *(__half2*)&Xs[r*136 + 2*lane] = __floats2half2_rn(d0*rs*gv.x + bv.x, d1*rs*gv.y + bv.y);
    }
    __syncthreads();
    // t = relu(Xs @ ws1 + bs1)   (B from global)
    {
        float b0 = bs1[w*16 + n];
        v4f acc = (v4f){b0, b0, b0, b0};
        const __half* wp = ws1T + (size_t)(w*16 + n)*128 + quad*8;
        #pragma unroll
        for (int ks = 0; ks < 4; ks++) {
            v8h a  = *(const v8h*)&Xs[n*136 + ks*32 + quad*8];
            v8h bf = *(const v8h*)(wp + ks*32);
            acc = __builtin_amdgcn_mfma_f32_16x16x32_f16(a, bf, acc, 0, 0, 0);
        }
        #pragma unroll
        for (int r = 0; r < 4; r++)
            Ts[(quad*4 + r)*136 + w*16 + n] = (_Float16)fmaxf(acc[r], 0.f);
    }
    __syncthreads();
    // Crow[:,0:128] = h + t @ ws2 + bs2   (B from global)
    {
        float b0 = bs2[w*16 + n];
        v4f acc = (v4f){b0, b0, b0, b0};
        const __half* wp = ws2T + (size_t)(w*16 + n)*128 + quad*8;
        #pragma unroll
        for (int ks = 0; ks < 4; ks++) {
            v8h a  = *(const v8h*)&Ts[n*136 + ks*32 + quad*8];
            v8h bf = *(const v8h*)(wp + ks*32);
            acc = __builtin_amdgcn_mfma_f32_16x16x32_f16(a, bf, acc, 0, 0, 0);
        }
        #pragma unroll
        for (int r = 0; r < 4; r++) {
            int rr = quad*4 + r, col = w*16 + n;
            Crow[rr*260 + col] = Hrow[rr*132 + col] + acc[r];
        }
    }
    __syncthreads();
    // LN(256) -> Xa (2 rows per wave)
    #pragma unroll
    for (int rr = 0; rr < 2; rr++) {
        int r = w*2 + rr;
        float4 v = *(const float4*)&Crow[r*260 + 4*lane];
        float mu = waveAllSum(v.x + v.y + v.z + v.w) * (1.f/256.f);
        float d0 = v.x-mu, d1 = v.y-mu, d2 = v.z-mu, d3 = v.w-mu;
        float var = waveAllSum(d0*d0 + d1*d1 + d2*d2 + d3*d3) * (1.f/256.f);
        float rs = rsqrtf(var + EPSLN);
        float4 gv = *(const float4*)&g[4*lane];
        float4 bv = *(const float4*)&bb[4*lane];
        *(__half2*)&Xa[r*264 + 4*lane]     = __floats2half2_rn(d0*rs*gv.x + bv.x, d1*rs*gv.y + bv.y);
        *(__half2*)&Xa[r*264 + 4*lane + 2] = __floats2half2_rn(d2*rs*gv.z + bv.z, d3*rs*gv.w + bv.w);
    }
    __syncthreads();
    // u = relu(Xa @ wu1 + bu1)   (B from global, 8 ks, partial unroll)
    {
        float b0 = bu1[w*16 + n];
        v4f acc = (v4f){b0, b0, b0, b0};
        const __half* wp = wu1T + (size_t)(w*16 + n)*256 + quad*8;
        const _Float16* xp = &Xa[n*264 + quad*8];
        #pragma unroll 4
        for (int ks = 0; ks < 8; ks++) {
            v8h a  = *(const v8h*)(xp + ks*32);
            v8h bf = *(const v8h*)(wp + ks*32);
            acc = __builtin_amdgcn_mfma_f32_16x16x32_f16(a, bf, acc, 0, 0, 0);
        }
        #pragma unroll
        for (int r = 0; r < 4; r++)
            Ut[(quad*4 + r)*136 + w*16 + n] = (_Float16)fmaxf(acc[r], 0.f);
    }
    __syncthreads();
    // hout = h + u @ wu2 + bu2   (B from global)
    {
        float b0 = bu2[w*16 + n];
        v4f acc = (v4f){b0, b0, b0, b0};
        const __half* wp = wu2T + (size_t)(w*16 + n)*128 + quad*8;
        #pragma unroll
        for (int ks = 0; ks < 4; ks++) {
            v8h a  = *(const v8h*)&Ut[n*136 + ks*32 + quad*8];
            v8h bf = *(const v8h*)(wp + ks*32);
            acc = __builtin_amdgcn_mfma_f32_16x16x32_f16(a, bf, acc, 0, 0, 0);
        }
        #pragma unroll
        for (int r = 0; r < 4; r++) {
            int rr = quad*4 + r, col = w*16 + n;
            hout[(size_t)(row0 + rr)*128 + col] = Hrow[rr*132 + col] + acc[r];
        }
    }
}

// ---------- launch ----------
extern "C" void kernel_launch(void* const* d_in, const int* in_sizes, int n_in,
                              void* d_out, int out_size, void* d_ws, size_t ws_size,
                              hipStream_t stream) {
    const float* slots = (const float*)d_in[0];
    const float* ep    = (const float*)d_in[1];
    const float* et    = (const float*)d_in[2];
    const float* ls_g  = (const float*)d_in[3];
    const float* ls_b  = (const float*)d_in[4];
    const float* ws1   = (const float*)d_in[5];
    const float* bs1   = (const float*)d_in[6];
    const float* ws2   = (const float*)d_in[7];
    const float* bs2   = (const float*)d_in[8];
    const float* wi1   = (const float*)d_in[9];
    const float* bi1   = (const float*)d_in[10];
    const float* wi2   = (const float*)d_in[11];
    const float* bi2   = (const float*)d_in[12];
    const float* wi3   = (const float*)d_in[13];
    const float* bi3   = (const float*)d_in[14];
    const float* lu_g  = (const float*)d_in[15];
    const float* lu_b  = (const float*)d_in[16];
    const float* wu1   = (const float*)d_in[17];
    const float* bu1   = (const float*)d_in[18];
    const float* wu2   = (const float*)d_in[19];
    const float* bu2   = (const float*)d_in[20];
    float* out = (float*)d_out;

    char* p = (char*)d_ws;
    float*  h_buf   = (float*)p;   p += (size_t)NSLOT*DDIM*4;
    __half* Ycat    = (__half*)p;  p += (size_t)NSLOT*YROW*2;
    __half* wPre    = (__half*)p;  p += (size_t)TTYPE*BATCH*4096*2;
    __half* ws1T    = (__half*)p;  p += 128*128*2;
    __half* wi1catT = (__half*)p;  p += 1024*128*2;
    __half* ws2T    = (__half*)p;  p += 128*128*2;
    __half* wu1T    = (__half*)p;  p += 128*256*2;
    __half* wu2T    = (__half*)p;  p += 128*128*2;
    __half* w3catT  = (__half*)p;  p += 128*YROW*2;
    __half* w2T16   = (__half*)p;  p += 4*128*128*2;
    float*  biascat = (float*)p;   p += 1024*4;

    k_wconv<<<22 + 256, 256, 0, stream>>>(ws1, wi1, ws2, wu1, wu2, wi3, wi2, bi1, bi3,
                                          ep, et, ws1T, wi1catT, ws2T, wu1T, wu2T,
                                          w3catT, w2T16, biascat, wPre);

    for (int mp = 0; mp < 2; mp++) {
        const float* h = (mp == 0) ? slots : h_buf;
        float* hout = (mp == 0) ? h_buf : out;
        k_pair<<<BATCH*TTYPE, 512, 0, stream>>>(h, wi1catT, biascat, w2T16, bi2, wPre, Ycat);
        k_mega<<<NSLOT/16, 512, 0, stream>>>(Ycat, w3catT, ls_g, ls_b, ws1T, bs1, ws2T, bs2,
                                             lu_g, lu_b, wu1T, bu1, wu2T, bu2, h, hout);
    }
}

// Round 12
// 217.004 us; speedup vs baseline: 1.7122x; 1.0276x over previous
//
#include <hip/hip_runtime.h>
#include <hip/hip_fp16.h>

#define BATCH 64
#define KSLOT 64
#define DDIM  128
#define HDIM  128
#define TTYPE 4
#define NSLOT (BATCH*KSLOT)
#define EPSLN 1e-5f
#define YROW  544   // 4*128 y + 4 wsum + 28 pad (pad zeroed by k_pair, killed by zero weight cols)

typedef _Float16 v8h __attribute__((ext_vector_type(8)));
typedef _Float16 v4h __attribute__((ext_vector_type(4)));
typedef _Float16 v2h __attribute__((ext_vector_type(2)));
typedef float    v4f __attribute__((ext_vector_type(4)));

__device__ __forceinline__ float waveAllSum(float v) {
    #pragma unroll
    for (int m = 1; m < 64; m <<= 1) v += __shfl_xor(v, m, 64);
    return v;
}

// ---------- k_wconv: one-time weight transpose/convert + w-precompute (R8 exact) ----------
__global__ __launch_bounds__(256) void k_wconv(
        const float* __restrict__ ws1, const float* __restrict__ wi1,
        const float* __restrict__ ws2, const float* __restrict__ wu1,
        const float* __restrict__ wu2, const float* __restrict__ wi3,
        const float* __restrict__ wi2, const float* __restrict__ bi1,
        const float* __restrict__ bi3,
        const float* __restrict__ ep, const float* __restrict__ et,
        __half* __restrict__ ws1T, __half* __restrict__ wi1catT,
        __half* __restrict__ ws2T, __half* __restrict__ wu1T,
        __half* __restrict__ wu2T, __half* __restrict__ w3catT,
        __half* __restrict__ w2T16, float* __restrict__ biascat,
        __half* __restrict__ wPre) {
    __shared__ __align__(16) float tile[128*132];
    int bx = blockIdx.x, tid = threadIdx.x;
    if (bx >= 22) {
        int bx2 = bx - 22, b = bx2 >> 2, chunk = bx2 & 3;
        const float4* etb = (const float4*)(et + (size_t)b*16384);
        const float*  epb = ep + (size_t)b*4096;
        __half* w0 = wPre + ((size_t)0*BATCH + b)*4096;
        __half* w1 = wPre + ((size_t)1*BATCH + b)*4096;
        __half* w2 = wPre + ((size_t)2*BATCH + b)*4096;
        __half* w3 = wPre + ((size_t)3*BATCH + b)*4096;
        int c0 = chunk*1024;
        for (int c = c0 + tid; c < c0 + 1024; c += 256) {
            float wv = epb[c];
            float4 e = etb[c];
            w0[c] = __float2half(wv * e.x);
            w1[c] = __float2half(wv * e.y);
            w2[c] = __float2half(wv * e.z);
            w3[c] = __float2half(wv * e.w);
        }
        return;
    }
    if (bx == 21) {
        for (int idx = tid; idx < 128*32; idx += 256) {
            int o = idx >> 5, c = idx & 31;
            w3catT[(size_t)o*YROW + 512 + c] = (c < 4) ? __float2half(bi3[c*DDIM + o]) : __float2half(0.f);
        }
        for (int idx = tid; idx < 1024; idx += 256) {
            int th = idx >> 7, o = idx & 127;
            biascat[idx] = (th & 1) ? bi1[(th>>1)*HDIM + o] : 0.f;
        }
        return;
    }
    const float* src; __half* dst; int dstride = 128, dcol = 0;
    if (bx == 0)      { src = ws1; dst = ws1T; }
    else if (bx <= 8) { int th = bx-1, tau = th>>1, half = th&1;
                        src = wi1 + ((size_t)tau*256 + half*128)*128;
                        dst = wi1catT + (size_t)th*128*128; }
    else if (bx == 9) { src = ws2; dst = ws2T; }
    else if (bx ==10) { src = wu2; dst = wu2T; }
    else if (bx <=12) { int hh = bx-11; src = wu1 + (size_t)hh*128*128;
                        dst = wu1T; dstride = 256; dcol = hh*128; }
    else if (bx <=16) { int tau = bx-13; src = wi3 + (size_t)tau*16384;
                        dst = w3catT; dstride = YROW; dcol = tau*128; }
    else              { int tau = bx-17; src = wi2 + (size_t)tau*16384;
                        dst = w2T16 + (size_t)tau*16384; }
    for (int idx = tid; idx < 4096; idx += 256) {
        int r = idx >> 5, c4 = idx & 31;
        *(float4*)&tile[r*132 + c4*4] = *(const float4*)&src[(size_t)r*128 + c4*4];
    }
    __syncthreads();
    for (int idx = tid; idx < 8192; idx += 256) {
        int n = idx >> 6, kp = idx & 63;
        __half2 p = __floats2half2_rn(tile[(2*kp)*132 + n], tile[(2*kp+1)*132 + n]);
        *(__half2*)&dst[(size_t)n*dstride + dcol + 2*kp] = p;
    }
}

// ---------- k_pair v11: grid 512 (j-split) x 64-reg diet x 16-MFMA/iter waves ----------
// R2 proved: grid 512 + VGPR 60 + LDS 65024 -> 2 blocks/CU (occ 32%). This keeps that
// register/LDS point but with R4's wave layout (jt x oh x ihalf, 4 ot, 32 iters) and
// R11's in-loop LDS bfrag reads (keeps arch regs at ~64).
#define LROW 136
__global__ __launch_bounds__(512, 4) void k_pair(
        const float* __restrict__ h,        // [4096][128] fp32
        const __half* __restrict__ wi1catT, // [8][128 o][128 k]
        const float* __restrict__ biascat,  // [8*128]
        const __half* __restrict__ w2T16,   // [4][128][128]
        const float* __restrict__ bi2,
        const __half* __restrict__ wPre,    // [4][64][64 i][64 j] f16
        __half* __restrict__ Ycat) {        // [4096][YROW]
    __shared__ __align__(16) _Float16 U[HDIM*LROW];     // hs (rows 0..63) then w2T (128 rows) = 34816
    __shared__ __align__(16) _Float16 Cs[32*LROW];      //  8704 (block's 32 receivers)
    __shared__ __align__(16) _Float16 As[KSLOT*LROW];   // 17408 (all 64 senders; scratch after loop)
    __shared__ __align__(16) _Float16 wS[KSLOT*32];     //  4096 -> 65024 B total
    int bx = blockIdx.x;
    int jhalf = bx & 1, tau = (bx >> 1) & 3, b = bx >> 3;
    int tid = threadIdx.x, lane = tid & 63, w = tid >> 6;
    int quad = lane >> 4, n = lane & 15;
    int ihalf = w & 1, oh = (w >> 1) & 1, jt = w >> 2;

    // stage hs (all 64 rows) into U
    {
        int row = tid >> 3, c0 = (tid & 7)*16;
        const float* hp = &h[(size_t)(b*KSLOT + row)*128 + c0];
        #pragma unroll
        for (int q = 0; q < 4; q++) {
            float4 f = *(const float4*)&hp[q*4];
            *(__half2*)&U[row*LROW + c0 + q*4]     = __floats2half2_rn(f.x, f.y);
            *(__half2*)&U[row*LROW + c0 + q*4 + 2] = __floats2half2_rn(f.z, f.w);
        }
    }
    // stage wS: 64 senders x this block's 32 receivers
    if (tid < 256) {
        int i = tid >> 2, seg = (tid & 3)*8;
        *(v8h*)&wS[i*32 + seg] =
            *(const v8h*)&wPre[((size_t)tau*BATCH + b)*4096 + i*64 + jhalf*32 + seg];
    }
    __syncthreads();

    // phase 1: waves 0-3 -> As (64 senders); waves 4-5 -> Cs (32 receivers + bias)
    if (w < 6) {
        int isA = (w < 4);
        int rt  = isA ? w : (w - 4);
        int hrow0 = isA ? rt*16 : (jhalf*32 + rt*16);
        const __half* wb = wi1catT + (size_t)(tau*2 + (isA ? 0 : 1))*128*128;
        const float* bcp = biascat + (tau*2 + (isA ? 0 : 1))*128;
        _Float16* dst = isA ? (As + rt*16*LROW) : (Cs + rt*16*LROW);
        v8h afr[4];
        #pragma unroll
        for (int ks = 0; ks < 4; ks++)
            afr[ks] = *(const v8h*)&U[(hrow0 + n)*LROW + ks*32 + quad*8];
        #pragma unroll
        for (int ot = 0; ot < 8; ot++) {
            float b0 = bcp[ot*16 + n];
            v4f acc = (v4f){b0, b0, b0, b0};
            #pragma unroll
            for (int ks = 0; ks < 4; ks++)
                acc = __builtin_amdgcn_mfma_f32_16x16x32_f16(
                    afr[ks], *(const v8h*)&wb[(size_t)(ot*16 + n)*128 + ks*32 + quad*8], acc, 0, 0, 0);
            #pragma unroll
            for (int r = 0; r < 4; r++)
                dst[(quad*4 + r)*LROW + ot*16 + n] = (_Float16)acc[r];
        }
    }
    __syncthreads();
    // hs dead -> w2T into U straight from global (no reg-staging peak)
    #pragma unroll
    for (int k2 = 0; k2 < 4; k2++) {
        int idx = tid + k2*512;
        int o = idx >> 4, seg = (idx & 15)*8;
        *(v8h*)&U[o*LROW + seg] = *(const v8h*)&w2T16[((size_t)tau*128 + o)*128 + seg];
    }
    __syncthreads();

    // phase 2: 32-iter i-loop (this wave's ihalf); bfrag from LDS each iter
    v8h cfrag[4];
    #pragma unroll
    for (int ks = 0; ks < 4; ks++)
        cfrag[ks] = *(const v8h*)&Cs[(jt*16 + n)*LROW + ks*32 + quad*8];
    v4f biasvec[4];
    #pragma unroll
    for (int ot = 0; ot < 4; ot++) {
        float b0 = bi2[tau*HDIM + oh*64 + ot*16 + n];
        biasvec[ot] = (v4f){b0, b0, b0, b0};
    }

    v4h yacch[4];
    #pragma unroll
    for (int ot = 0; ot < 4; ot++) yacch[ot] = (v4h){0,0,0,0};
    v4h wsacch = (v4h){0,0,0,0};
    const v8h zero8 = {0,0,0,0,0,0,0,0};
    const v4h zero4h = {0,0,0,0};

    const _Float16* ub = &U[(oh*64 + n)*LROW + quad*8];   // bfrag base; (ot,ks) imm offsets
    int ibase = ihalf*32;

    for (int ii = 0; ii < 32; ++ii) {
        int i = ibase + ii;
        v8h a[4];
        #pragma unroll
        for (int ks = 0; ks < 4; ks++)
            a[ks] = *(const v8h*)&As[i*LROW + ks*32 + quad*8];
        v4h wv = *(const v4h*)&wS[i*32 + jt*16 + quad*4];
        v8h x1[4];
        #pragma unroll
        for (int ks = 0; ks < 4; ks++)
            x1[ks] = __builtin_elementwise_max(a[ks] + cfrag[ks], zero8);
        v4f acc0 = biasvec[0], acc1 = biasvec[1], acc2 = biasvec[2], acc3 = biasvec[3];
        #pragma unroll
        for (int ks = 0; ks < 4; ks++) {
            acc0 = __builtin_amdgcn_mfma_f32_16x16x32_f16(x1[ks], *(const v8h*)(ub + 0*16*LROW + ks*32), acc0, 0, 0, 0);
            acc1 = __builtin_amdgcn_mfma_f32_16x16x32_f16(x1[ks], *(const v8h*)(ub + 1*16*LROW + ks*32), acc1, 0, 0, 0);
            acc2 = __builtin_amdgcn_mfma_f32_16x16x32_f16(x1[ks], *(const v8h*)(ub + 2*16*LROW + ks*32), acc2, 0, 0, 0);
            acc3 = __builtin_amdgcn_mfma_f32_16x16x32_f16(x1[ks], *(const v8h*)(ub + 3*16*LROW + ks*32), acc3, 0, 0, 0);
        }
        #define EPI(ACC, OT) { \
            v2h lo = __builtin_bit_cast(v2h, __builtin_amdgcn_cvt_pkrtz(ACC[0], ACC[1])); \
            v2h hi = __builtin_bit_cast(v2h, __builtin_amdgcn_cvt_pkrtz(ACC[2], ACC[3])); \
            v4h rel = {lo[0], lo[1], hi[0], hi[1]}; \
            rel = __builtin_elementwise_max(rel, zero4h); \
            yacch[OT] = yacch[OT] + wv * rel; }
        EPI(acc0, 0) EPI(acc1, 1) EPI(acc2, 2) EPI(acc3, 3)
        #undef EPI
        wsacch = wsacch + wv;
    }

    // cross-ihalf reduction through As scratch (R4-verified mechanism)
    __syncthreads();
    v4h* sc = (v4h*)As;
    int scbase = ((jt*2 + oh)*64 + lane)*5;
    if (ihalf == 1) {
        #pragma unroll
        for (int ot = 0; ot < 4; ot++) sc[scbase + ot] = yacch[ot];
        sc[scbase + 4] = wsacch;
    }
    __syncthreads();
    if (ihalf == 0) {
        #pragma unroll
        for (int ot = 0; ot < 4; ot++) yacch[ot] = yacch[ot] + sc[scbase + ot];
        wsacch = wsacch + sc[scbase + 4];

        #pragma unroll
        for (int r = 0; r < 4; r++) {
            int j = jhalf*32 + jt*16 + quad*4 + r;
            __half* yb = Ycat + (size_t)(b*KSLOT + j)*YROW + tau*128 + oh*64;
            #pragma unroll
            for (int ot = 0; ot < 4; ot++)
                yb[ot*16 + n] = __float2half((float)yacch[ot][r]);
        }
        if (oh == 0 && n == 0) {
            #pragma unroll
            for (int r = 0; r < 4; r++) {
                int j = jhalf*32 + jt*16 + quad*4 + r;
                Ycat[(size_t)(b*KSLOT + j)*YROW + 512 + tau] = __float2half((float)wsacch[r]);
            }
        }
        // zero pad cols 516..543 once per row (tau==0 blocks own it)
        if (tau == 0 && oh == 1 && n == 0) {
            const v4h z4 = {0,0,0,0};
            #pragma unroll
            for (int r = 0; r < 4; r++) {
                int j = jhalf*32 + jt*16 + quad*4 + r;
                _Float16* pz = (_Float16*)(Ycat + (size_t)(b*KSLOT + j)*YROW + 516);
                #pragma unroll
                for (int c = 0; c < 28; c += 4) *(v4h*)&pz[c] = z4;
            }
        }
    }
}

// ---------- k_mega v2 (R8 exact): B-fragments from global (L2), no weight preload ----------
__global__ __launch_bounds__(512, 2) void k_mega(
        const __half* __restrict__ Ycat, const __half* __restrict__ w3catT,
        const float* __restrict__ ls_g, const float* __restrict__ ls_b,
        const __half* __restrict__ ws1T, const float* __restrict__ bs1,
        const __half* __restrict__ ws2T, const float* __restrict__ bs2,
        const float* __restrict__ g, const float* __restrict__ bb,
        const __half* __restrict__ wu1T, const float* __restrict__ bu1,
        const __half* __restrict__ wu2T, const float* __restrict__ bu2,
        const float* __restrict__ h, float* __restrict__ hout) {
    __shared__ __align__(16) _Float16 Ys[16*552];    // 17664
    __shared__ __align__(16) float    Crow[16*260];  // 16640
    __shared__ __align__(16) float    Hrow[16*132];  //  8448
    __shared__ __align__(16) _Float16 Xs[16*136];    //  4352
    __shared__ __align__(16) _Float16 Ts[16*136];    //  4352
    __shared__ __align__(16) _Float16 Xa[16*264];    //  8448
    __shared__ __align__(16) _Float16 Ut[16*136];    //  4352  -> 64256 B
    int tid = threadIdx.x, lane = tid & 63, w = tid >> 6;
    int n = lane & 15, quad = lane >> 4;
    int row0 = blockIdx.x*16;

    for (int u = tid; u < 1024; u += 512) {
        int r = u >> 6, seg = (u & 63)*8;
        *(v8h*)&Ys[r*552 + seg] = *(const v8h*)&Ycat[(size_t)(row0 + r)*YROW + seg];
    }
    if (tid < 64) {
        int r = tid >> 2, seg = 512 + (tid & 3)*8;
        *(v8h*)&Ys[r*552 + seg] = *(const v8h*)&Ycat[(size_t)(row0 + r)*YROW + seg];
    }
    {
        int r = tid >> 5, c4 = (tid & 31)*4;
        *(float4*)&Hrow[r*132 + c4] = *(const float4*)&h[(size_t)(row0 + r)*128 + c4];
    }
    __syncthreads();
    // dinter = Ys @ w3catT^T  -> Crow[:,128:256]   (B from global, partial unroll)
    {
        const __half* wp = w3catT + (size_t)(w*16 + n)*YROW + quad*8;
        const _Float16* yp = &Ys[n*552 + quad*8];
        v4f acc = (v4f){0.f,0.f,0.f,0.f};
        #pragma unroll 4
        for (int ks = 0; ks < 17; ks++) {
            v8h a  = *(const v8h*)(yp + ks*32);
            v8h bf = *(const v8h*)(wp + ks*32);
            acc = __builtin_amdgcn_mfma_f32_16x16x32_f16(a, bf, acc, 0, 0, 0);
        }
        #pragma unroll
        for (int r = 0; r < 4; r++)
            Crow[(quad*4 + r)*260 + 128 + w*16 + n] = acc[r];
    }
    // LN(128) of h -> Xs (2 rows per wave)
    #pragma unroll
    for (int rr = 0; rr < 2; rr++) {
        int r = w*2 + rr;
        float x0 = Hrow[r*132 + 2*lane], x1 = Hrow[r*132 + 2*lane + 1];
        float mu = waveAllSum(x0 + x1) * (1.f/128.f);
        float d0 = x0 - mu, d1 = x1 - mu;
        float var = waveAllSum(d0*d0 + d1*d1) * (1.f/128.f);
        float rs = rsqrtf(var + EPSLN);
        float2 gv = *(const float2*)&ls_g[2*lane];
        float2 bv = *(const float2*)&ls_b[2*lane];
        *(__half2*)&Xs[r*136 + 2*lane] = __floats2half2_rn(d0*rs*gv.x + bv.x, d1*rs*gv.y + bv.y);
    }
    __syncthreads();
    // t = relu(Xs @ ws1 + bs1)   (B from global)
    {
        float b0 = bs1[w*16 + n];
        v4f acc = (v4f){b0, b0, b0, b0};
        const __half* wp = ws1T + (size_t)(w*16 + n)*128 + quad*8;
        #pragma unroll
        for (int ks = 0; ks < 4; ks++) {
            v8h a  = *(const v8h*)&Xs[n*136 + ks*32 + quad*8];
            v8h bf = *(const v8h*)(wp + ks*32);
            acc = __builtin_amdgcn_mfma_f32_16x16x32_f16(a, bf, acc, 0, 0, 0);
        }
        #pragma unroll
        for (int r = 0; r < 4; r++)
            Ts[(quad*4 + r)*136 + w*16 + n] = (_Float16)fmaxf(acc[r], 0.f);
    }
    __syncthreads();
    // Crow[:,0:128] = h + t @ ws2 + bs2   (B from global)
    {
        float b0 = bs2[w*16 + n];
        v4f acc = (v4f){b0, b0, b0, b0};
        const __half* wp = ws2T + (size_t)(w*16 + n)*128 + quad*8;
        #pragma unroll
        for (int ks = 0; ks < 4; ks++) {
            v8h a  = *(const v8h*)&Ts[n*136 + ks*32 + quad*8];
            v8h bf = *(const v8h*)(wp + ks*32);
            acc = __builtin_amdgcn_mfma_f32_16x16x32_f16(a, bf, acc, 0, 0, 0);
        }
        #pragma unroll
        for (int r = 0; r < 4; r++) {
            int rr = quad*4 + r, col = w*16 + n;
            Crow[rr*260 + col] = Hrow[rr*132 + col] + acc[r];
        }
    }
    __syncthreads();
    // LN(256) -> Xa (2 rows per wave)
    #pragma unroll
    for (int rr = 0; rr < 2; rr++) {
        int r = w*2 + rr;
        float4 v = *(const float4*)&Crow[r*260 + 4*lane];
        float mu = waveAllSum(v.x + v.y + v.z + v.w) * (1.f/256.f);
        float d0 = v.x-mu, d1 = v.y-mu, d2 = v.z-mu, d3 = v.w-mu;
        float var = waveAllSum(d0*d0 + d1*d1 + d2*d2 + d3*d3) * (1.f/256.f);
        float rs = rsqrtf(var + EPSLN);
        float4 gv = *(const float4*)&g[4*lane];
        float4 bv = *(const float4*)&bb[4*lane];
        *(__half2*)&Xa[r*264 + 4*lane]     = __floats2half2_rn(d0*rs*gv.x + bv.x, d1*rs*gv.y + bv.y);
        *(__half2*)&Xa[r*264 + 4*lane + 2] = __floats2half2_rn(d2*rs*gv.z + bv.z, d3*rs*gv.w + bv.w);
    }
    __syncthreads();
    // u = relu(Xa @ wu1 + bu1)   (B from global, 8 ks, partial unroll)
    {
        float b0 = bu1[w*16 + n];
        v4f acc = (v4f){b0, b0, b0, b0};
        const __half* wp = wu1T + (size_t)(w*16 + n)*256 + quad*8;
        const _Float16* xp = &Xa[n*264 + quad*8];
        #pragma unroll 4
        for (int ks = 0; ks < 8; ks++) {
            v8h a  = *(const v8h*)(xp + ks*32);
            v8h bf = *(const v8h*)(wp + ks*32);
            acc = __builtin_amdgcn_mfma_f32_16x16x32_f16(a, bf, acc, 0, 0, 0);
        }
        #pragma unroll
        for (int r = 0; r < 4; r++)
            Ut[(quad*4 + r)*136 + w*16 + n] = (_Float16)fmaxf(acc[r], 0.f);
    }
    __syncthreads();
    // hout = h + u @ wu2 + bu2   (B from global)
    {
        float b0 = bu2[w*16 + n];
        v4f acc = (v4f){b0, b0, b0, b0};
        const __half* wp = wu2T + (size_t)(w*16 + n)*128 + quad*8;
        #pragma unroll
        for (int ks = 0; ks < 4; ks++) {
            v8h a  = *(const v8h*)&Ut[n*136 + ks*32 + quad*8];
            v8h bf = *(const v8h*)(wp + ks*32);
            acc = __builtin_amdgcn_mfma_f32_16x16x32_f16(a, bf, acc, 0, 0, 0);
        }
        #pragma unroll
        for (int r = 0; r < 4; r++) {
            int rr = quad*4 + r, col = w*16 + n;
            hout[(size_t)(row0 + rr)*128 + col] = Hrow[rr*132 + col] + acc[r];
        }
    }
}

// ---------- launch ----------
extern "C" void kernel_launch(void* const* d_in, const int* in_sizes, int n_in,
                              void* d_out, int out_size, void* d_ws, size_t ws_size,
                              hipStream_t stream) {
    const float* slots = (const float*)d_in[0];
    const float* ep    = (const float*)d_in[1];
    const float* et    = (const float*)d_in[2];
    const float* ls_g  = (const float*)d_in[3];
    const float* ls_b  = (const float*)d_in[4];
    const float* ws1   = (const float*)d_in[5];
    const float* bs1   = (const float*)d_in[6];
    const float* ws2   = (const float*)d_in[7];
    const float* bs2   = (const float*)d_in[8];
    const float* wi1   = (const float*)d_in[9];
    const float* bi1   = (const float*)d_in[10];
    const float* wi2   = (const float*)d_in[11];
    const float* bi2   = (const float*)d_in[12];
    const float* wi3   = (const float*)d_in[13];
    const float* bi3   = (const float*)d_in[14];
    const float* lu_g  = (const float*)d_in[15];
    const float* lu_b  = (const float*)d_in[16];
    const float* wu1   = (const float*)d_in[17];
    const float* bu1   = (const float*)d_in[18];
    const float* wu2   = (const float*)d_in[19];
    const float* bu2   = (const float*)d_in[20];
    float* out = (float*)d_out;

    char* p = (char*)d_ws;
    float*  h_buf   = (float*)p;   p += (size_t)NSLOT*DDIM*4;
    __half* Ycat    = (__half*)p;  p += (size_t)NSLOT*YROW*2;
    __half* wPre    = (__half*)p;  p += (size_t)TTYPE*BATCH*4096*2;
    __half* ws1T    = (__half*)p;  p += 128*128*2;
    __half* wi1catT = (__half*)p;  p += 1024*128*2;
    __half* ws2T    = (__half*)p;  p += 128*128*2;
    __half* wu1T    = (__half*)p;  p += 128*256*2;
    __half* wu2T    = (__half*)p;  p += 128*128*2;
    __half* w3catT  = (__half*)p;  p += 128*YROW*2;
    __half* w2T16   = (__half*)p;  p += 4*128*128*2;
    float*  biascat = (float*)p;   p += 1024*4;

    k_wconv<<<22 + 256, 256, 0, stream>>>(ws1, wi1, ws2, wu1, wu2, wi3, wi2, bi1, bi3,
                                          ep, et, ws1T, wi1catT, ws2T, wu1T, wu2T,
                                          w3catT, w2T16, biascat, wPre);

    for (int mp = 0; mp < 2; mp++) {
        const float* h = (mp == 0) ? slots : h_buf;
        float* hout = (mp == 0) ? h_buf : out;
        k_pair<<<BATCH*TTYPE*2, 512, 0, stream>>>(h, wi1catT, biascat, w2T16, bi2, wPre, Ycat);
        k_mega<<<NSLOT/16, 512, 0, stream>>>(Ycat, w3catT, ls_g, ls_b, ws1T, bs1, ws2T, bs2,
                                             lu_g, lu_b, wu1T, bu1, wu2T, bu2, h, hout);
    }
}

// Round 13
// 199.149 us; speedup vs baseline: 1.8657x; 1.0897x over previous
//
#include <hip/hip_runtime.h>
#include <hip/hip_fp16.h>

#define BATCH 64
#define KSLOT 64
#define DDIM  128
#define HDIM  128
#define TTYPE 4
#define NSLOT (BATCH*KSLOT)
#define EPSLN 1e-5f
#define YROW  544   // 4*128 y + 4 wsum + 28 pad (pad zeroed by k_pair, killed by zero weight cols)

typedef _Float16 v8h __attribute__((ext_vector_type(8)));
typedef _Float16 v4h __attribute__((ext_vector_type(4)));
typedef _Float16 v2h __attribute__((ext_vector_type(2)));
typedef float    v4f __attribute__((ext_vector_type(4)));

__device__ __forceinline__ float waveAllSum(float v) {
    #pragma unroll
    for (int m = 1; m < 64; m <<= 1) v += __shfl_xor(v, m, 64);
    return v;
}

// ---------- k_wconv: one-time weight transpose/convert + w-precompute ----------
__global__ __launch_bounds__(256) void k_wconv(
        const float* __restrict__ ws1, const float* __restrict__ wi1,
        const float* __restrict__ ws2, const float* __restrict__ wu1,
        const float* __restrict__ wu2, const float* __restrict__ wi3,
        const float* __restrict__ wi2, const float* __restrict__ bi1,
        const float* __restrict__ bi3,
        const float* __restrict__ ep, const float* __restrict__ et,
        __half* __restrict__ ws1T, __half* __restrict__ wi1catT,
        __half* __restrict__ ws2T, __half* __restrict__ wu1T,
        __half* __restrict__ wu2T, __half* __restrict__ w3catT,
        __half* __restrict__ w2T16, float* __restrict__ biascat,
        __half* __restrict__ wPre) {
    __shared__ __align__(16) float tile[128*132];
    int bx = blockIdx.x, tid = threadIdx.x;
    if (bx >= 22) {
        int bx2 = bx - 22, b = bx2 >> 2, chunk = bx2 & 3;
        const float4* etb = (const float4*)(et + (size_t)b*16384);
        const float*  epb = ep + (size_t)b*4096;
        __half* w0 = wPre + ((size_t)0*BATCH + b)*4096;
        __half* w1 = wPre + ((size_t)1*BATCH + b)*4096;
        __half* w2 = wPre + ((size_t)2*BATCH + b)*4096;
        __half* w3 = wPre + ((size_t)3*BATCH + b)*4096;
        int c0 = chunk*1024;
        for (int c = c0 + tid; c < c0 + 1024; c += 256) {
            float wv = epb[c];
            float4 e = etb[c];
            w0[c] = __float2half(wv * e.x);
            w1[c] = __float2half(wv * e.y);
            w2[c] = __float2half(wv * e.z);
            w3[c] = __float2half(wv * e.w);
        }
        return;
    }
    if (bx == 21) {
        for (int idx = tid; idx < 128*32; idx += 256) {
            int o = idx >> 5, c = idx & 31;
            w3catT[(size_t)o*YROW + 512 + c] = (c < 4) ? __float2half(bi3[c*DDIM + o]) : __float2half(0.f);
        }
        for (int idx = tid; idx < 1024; idx += 256) {
            int th = idx >> 7, o = idx & 127;
            biascat[idx] = (th & 1) ? bi1[(th>>1)*HDIM + o] : 0.f;
        }
        return;
    }
    const float* src; __half* dst; int dstride = 128, dcol = 0;
    if (bx == 0)      { src = ws1; dst = ws1T; }
    else if (bx <= 8) { int th = bx-1, tau = th>>1, half = th&1;
                        src = wi1 + ((size_t)tau*256 + half*128)*128;
                        dst = wi1catT + (size_t)th*128*128; }
    else if (bx == 9) { src = ws2; dst = ws2T; }
    else if (bx ==10) { src = wu2; dst = wu2T; }
    else if (bx <=12) { int hh = bx-11; src = wu1 + (size_t)hh*128*128;
                        dst = wu1T; dstride = 256; dcol = hh*128; }
    else if (bx <=16) { int tau = bx-13; src = wi3 + (size_t)tau*16384;
                        dst = w3catT; dstride = YROW; dcol = tau*128; }
    else              { int tau = bx-17; src = wi2 + (size_t)tau*16384;
                        dst = w2T16 + (size_t)tau*16384; }
    for (int idx = tid; idx < 4096; idx += 256) {
        int r = idx >> 5, c4 = idx & 31;
        *(float4*)&tile[r*132 + c4*4] = *(const float4*)&src[(size_t)r*128 + c4*4];
    }
    __syncthreads();
    for (int idx = tid; idx < 8192; idx += 256) {
        int n = idx >> 6, kp = idx & 63;
        __half2 p = __floats2half2_rn(tile[(2*kp)*132 + n], tile[(2*kp+1)*132 + n]);
        *(__half2*)&dst[(size_t)n*dstride + dcol + 2*kp] = p;
    }
}

// ---------- k_pair: 2-wide software-pipelined inner loop (best measured: ~44 us) ----------
#define LROW 136

__device__ __forceinline__ void cluster4(v4f& p0, v4f& p1, v4f& p2, v4f& p3,
                                         const v8h x[4], const v8h bf[4][4],
                                         const v4f bias[4]) {
    p0 = bias[0]; p1 = bias[1]; p2 = bias[2]; p3 = bias[3];
    #pragma unroll
    for (int ks = 0; ks < 4; ks++) {
        p0 = __builtin_amdgcn_mfma_f32_16x16x32_f16(x[ks], bf[0][ks], p0, 0, 0, 0);
        p1 = __builtin_amdgcn_mfma_f32_16x16x32_f16(x[ks], bf[1][ks], p1, 0, 0, 0);
        p2 = __builtin_amdgcn_mfma_f32_16x16x32_f16(x[ks], bf[2][ks], p2, 0, 0, 0);
        p3 = __builtin_amdgcn_mfma_f32_16x16x32_f16(x[ks], bf[3][ks], p3, 0, 0, 0);
    }
}

__device__ __forceinline__ void epi4(v4h yacch[4], v4h& wsacch,
                                     const v4f& p0, const v4f& p1,
                                     const v4f& p2, const v4f& p3, v4h wv) {
    const v4h zero4h = {0,0,0,0};
    #define EPI1(P, OT) { \
        v2h lo = __builtin_bit_cast(v2h, __builtin_amdgcn_cvt_pkrtz(P[0], P[1])); \
        v2h hi = __builtin_bit_cast(v2h, __builtin_amdgcn_cvt_pkrtz(P[2], P[3])); \
        v4h rel = {lo[0], lo[1], hi[0], hi[1]}; \
        rel = __builtin_elementwise_max(rel, zero4h); \
        yacch[OT] = yacch[OT] + wv * rel; }
    EPI1(p0, 0) EPI1(p1, 1) EPI1(p2, 2) EPI1(p3, 3)
    #undef EPI1
    wsacch = wsacch + wv;
}

__global__ __launch_bounds__(512) void k_pair(
        const float* __restrict__ h,        // [4096][128] fp32
        const __half* __restrict__ wi1catT, // [8][128 o][128 k]
        const float* __restrict__ biascat,  // [8*128]
        const __half* __restrict__ w2T16,   // [4][128][128]
        const float* __restrict__ bi2,
        const __half* __restrict__ wPre,    // [4][64][64 i][64 j] f16
        __half* __restrict__ Ycat) {        // [4096][YROW]
    __shared__ __align__(16) _Float16 w2T[HDIM*LROW];   // 34816
    __shared__ __align__(16) _Float16 Cs[KSLOT*LROW];   // 17408
    __shared__ __align__(16) _Float16 As[KSLOT*LROW];   // 17408
    __shared__ __align__(16) _Float16 wS[KSLOT*KSLOT];  //  8192
    __shared__ __align__(16) _Float16 hs[KSLOT*136];    // 17408 -> 95232 B
    int bx = blockIdx.x, b = bx >> 2, tau = bx & 3;
    int tid = threadIdx.x, lane = tid & 63, w = tid >> 6;
    int jt = w >> 1, oh = w & 1, quad = lane >> 4, n = lane & 15;

    for (int idx = tid; idx < 2048; idx += 512) {
        int o = idx >> 4, seg = (idx & 15)*8;
        *(v8h*)&w2T[o*LROW + seg] = *(const v8h*)&w2T16[((size_t)tau*128 + o)*128 + seg];
    }
    {
        int row = tid >> 3, c0 = (tid & 7)*16;
        const float* hp = &h[(size_t)(b*KSLOT + row)*128 + c0];
        #pragma unroll
        for (int q = 0; q < 4; q++) {
            float4 f = *(const float4*)&hp[q*4];
            *(__half2*)&hs[row*136 + c0 + q*4]     = __floats2half2_rn(f.x, f.y);
            *(__half2*)&hs[row*136 + c0 + q*4 + 2] = __floats2half2_rn(f.z, f.w);
        }
    }
    {
        int base = tid*8;
        *(v8h*)&wS[base] = *(const v8h*)&wPre[((size_t)tau*BATCH + b)*4096 + base];
    }
    __syncthreads();

    // phase 1: As/Cs = hs @ wi1[tau] (+bias on C)
    {
        int hf = w >> 2, rt = w & 3;
        const __half* wb = wi1catT + (size_t)(tau*2 + hf)*128*128;
        const float* bcp = biascat + (tau*2 + hf)*128;
        _Float16* dst = hf ? Cs : As;
        v8h afr[4];
        #pragma unroll
        for (int ks = 0; ks < 4; ks++)
            afr[ks] = *(const v8h*)&hs[(rt*16 + n)*136 + ks*32 + quad*8];
        #pragma unroll
        for (int ot = 0; ot < 8; ot++) {
            float b0 = bcp[ot*16 + n];
            v4f acc = (v4f){b0, b0, b0, b0};
            #pragma unroll
            for (int ks = 0; ks < 4; ks++)
                acc = __builtin_amdgcn_mfma_f32_16x16x32_f16(
                    afr[ks], *(const v8h*)&wb[(size_t)(ot*16 + n)*128 + ks*32 + quad*8], acc, 0, 0, 0);
            #pragma unroll
            for (int r = 0; r < 4; r++)
                dst[(rt*16 + quad*4 + r)*LROW + ot*16 + n] = (_Float16)acc[r];
        }
    }
    __syncthreads();

    // phase 2: i-loop, 2-wide pipelined
    v8h bfrag[4][4];
    #pragma unroll
    for (int ot = 0; ot < 4; ot++)
        #pragma unroll
        for (int ks = 0; ks < 4; ks++)
            bfrag[ot][ks] = *(const v8h*)&w2T[(oh*64 + ot*16 + n)*LROW + ks*32 + quad*8];
    v8h cfrag[4];
    #pragma unroll
    for (int ks = 0; ks < 4; ks++)
        cfrag[ks] = *(const v8h*)&Cs[(jt*16 + n)*LROW + ks*32 + quad*8];
    v4f biasvec[4];
    #pragma unroll
    for (int ot = 0; ot < 4; ot++) {
        float b0 = bi2[tau*HDIM + oh*64 + ot*16 + n];
        biasvec[ot] = (v4f){b0, b0, b0, b0};
    }

    v4h yacch[4];
    #pragma unroll
    for (int ot = 0; ot < 4; ot++) yacch[ot] = (v4h){0,0,0,0};
    v4h wsacch = (v4h){0,0,0,0};
    const v8h zero8 = {0,0,0,0,0,0,0,0};

    #define LOADA(DST, WV, I) { int _i = (I); \
        DST[0] = *(const v8h*)&As[_i*LROW +  0 + quad*8]; \
        DST[1] = *(const v8h*)&As[_i*LROW + 32 + quad*8]; \
        DST[2] = *(const v8h*)&As[_i*LROW + 64 + quad*8]; \
        DST[3] = *(const v8h*)&As[_i*LROW + 96 + quad*8]; \
        WV = *(const v4h*)&wS[_i*KSLOT + jt*16 + quad*4]; }

    v8h aA[4], aB[4], xA[4], xB[4];
    v4h wvA, wvB, wvEA, wvEB;
    LOADA(aA, wvA, 0)
    LOADA(aB, wvB, 1)
    #pragma unroll
    for (int ks = 0; ks < 4; ks++)
        xA[ks] = __builtin_elementwise_max(aA[ks] + cfrag[ks], zero8);
    v4f pA0, pA1, pA2, pA3, pB0, pB1, pB2, pB3;

    for (int ii = 0; ii < 32; ++ii) {
        int i = ii*2;
        // --- even half: i ---
        wvEA = wvA;
        { int i2 = (i+2 < 64) ? (i+2) : 63; LOADA(aA, wvA, i2) }
        cluster4(pA0, pA1, pA2, pA3, xA, bfrag, biasvec);
        #pragma unroll
        for (int ks = 0; ks < 4; ks++)
            xB[ks] = __builtin_elementwise_max(aB[ks] + cfrag[ks], zero8);
        epi4(yacch, wsacch, pA0, pA1, pA2, pA3, wvEA);
        // --- odd half: i+1 ---
        wvEB = wvB;
        { int i3 = (i+3 < 64) ? (i+3) : 63; LOADA(aB, wvB, i3) }
        cluster4(pB0, pB1, pB2, pB3, xB, bfrag, biasvec);
        #pragma unroll
        for (int ks = 0; ks < 4; ks++)
            xA[ks] = __builtin_elementwise_max(aA[ks] + cfrag[ks], zero8);
        epi4(yacch, wsacch, pB0, pB1, pB2, pB3, wvEB);
    }
    #undef LOADA

    #pragma unroll
    for (int r = 0; r < 4; r++) {
        int j = jt*16 + quad*4 + r;
        __half* yb = Ycat + (size_t)(b*KSLOT + j)*YROW + tau*128 + oh*64;
        #pragma unroll
        for (int ot = 0; ot < 4; ot++)
            yb[ot*16 + n] = __float2half((float)yacch[ot][r]);
    }
    if (oh == 0 && n == 0) {
        #pragma unroll
        for (int r = 0; r < 4; r++)
            Ycat[(size_t)(b*KSLOT + jt*16 + quad*4 + r)*YROW + 512 + tau] = __float2half((float)wsacch[r]);
    }
    // zero pad cols 516..543 once per row (tau==0 blocks own it)
    if (tau == 0 && oh == 1 && n == 0) {
        const v4h z4 = {0,0,0,0};
        #pragma unroll
        for (int r = 0; r < 4; r++) {
            _Float16* pz = (_Float16*)(Ycat + (size_t)(b*KSLOT + jt*16 + quad*4 + r)*YROW + 516);
            #pragma unroll
            for (int c = 0; c < 28; c += 4) *(v4h*)&pz[c] = z4;
        }
    }
}

// ---------- k_mega v2: B-fragments from global (L2), no weight preload ----------
__global__ __launch_bounds__(512, 2) void k_mega(
        const __half* __restrict__ Ycat, const __half* __restrict__ w3catT,
        const float* __restrict__ ls_g, const float* __restrict__ ls_b,
        const __half* __restrict__ ws1T, const float* __restrict__ bs1,
        const __half* __restrict__ ws2T, const float* __restrict__ bs2,
        const float* __restrict__ g, const float* __restrict__ bb,
        const __half* __restrict__ wu1T, const float* __restrict__ bu1,
        const __half* __restrict__ wu2T, const float* __restrict__ bu2,
        const float* __restrict__ h, float* __restrict__ hout) {
    __shared__ __align__(16) _Float16 Ys[16*552];    // 17664
    __shared__ __align__(16) float    Crow[16*260];  // 16640
    __shared__ __align__(16) float    Hrow[16*132];  //  8448
    __shared__ __align__(16) _Float16 Xs[16*136];    //  4352
    __shared__ __align__(16) _Float16 Ts[16*136];    //  4352
    __shared__ __align__(16) _Float16 Xa[16*264];    //  8448
    __shared__ __align__(16) _Float16 Ut[16*136];    //  4352  -> 64256 B
    int tid = threadIdx.x, lane = tid & 63, w = tid >> 6;
    int n = lane & 15, quad = lane >> 4;
    int row0 = blockIdx.x*16;

    for (int u = tid; u < 1024; u += 512) {
        int r = u >> 6, seg = (u & 63)*8;
        *(v8h*)&Ys[r*552 + seg] = *(const v8h*)&Ycat[(size_t)(row0 + r)*YROW + seg];
    }
    if (tid < 64) {
        int r = tid >> 2, seg = 512 + (tid & 3)*8;
        *(v8h*)&Ys[r*552 + seg] = *(const v8h*)&Ycat[(size_t)(row0 + r)*YROW + seg];
    }
    {
        int r = tid >> 5, c4 = (tid & 31)*4;
        *(float4*)&Hrow[r*132 + c4] = *(const float4*)&h[(size_t)(row0 + r)*128 + c4];
    }
    __syncthreads();
    // dinter = Ys @ w3catT^T  -> Crow[:,128:256]   (B from global, partial unroll)
    {
        const __half* wp = w3catT + (size_t)(w*16 + n)*YROW + quad*8;
        const _Float16* yp = &Ys[n*552 + quad*8];
        v4f acc = (v4f){0.f,0.f,0.f,0.f};
        #pragma unroll 4
        for (int ks = 0; ks < 17; ks++) {
            v8h a  = *(const v8h*)(yp + ks*32);
            v8h bf = *(const v8h*)(wp + ks*32);
            acc = __builtin_amdgcn_mfma_f32_16x16x32_f16(a, bf, acc, 0, 0, 0);
        }
        #pragma unroll
        for (int r = 0; r < 4; r++)
            Crow[(quad*4 + r)*260 + 128 + w*16 + n] = acc[r];
    }
    // LN(128) of h -> Xs (2 rows per wave)
    #pragma unroll
    for (int rr = 0; rr < 2; rr++) {
        int r = w*2 + rr;
        float x0 = Hrow[r*132 + 2*lane], x1 = Hrow[r*132 + 2*lane + 1];
        float mu = waveAllSum(x0 + x1) * (1.f/128.f);
        float d0 = x0 - mu, d1 = x1 - mu;
        float var = waveAllSum(d0*d0 + d1*d1) * (1.f/128.f);
        float rs = rsqrtf(var + EPSLN);
        float2 gv = *(const float2*)&ls_g[2*lane];
        float2 bv = *(const float2*)&ls_b[2*lane];
        *(__half2*)&Xs[r*136 + 2*lane] = __floats2half2_rn(d0*rs*gv.x + bv.x, d1*rs*gv.y + bv.y);
    }
    __syncthreads();
    // t = relu(Xs @ ws1 + bs1)   (B from global)
    {
        float b0 = bs1[w*16 + n];
        v4f acc = (v4f){b0, b0, b0, b0};
        const __half* wp = ws1T + (size_t)(w*16 + n)*128 + quad*8;
        #pragma unroll
        for (int ks = 0; ks < 4; ks++) {
            v8h a  = *(const v8h*)&Xs[n*136 + ks*32 + quad*8];
            v8h bf = *(const v8h*)(wp + ks*32);
            acc = __builtin_amdgcn_mfma_f32_16x16x32_f16(a, bf, acc, 0, 0, 0);
        }
        #pragma unroll
        for (int r = 0; r < 4; r++)
            Ts[(quad*4 + r)*136 + w*16 + n] = (_Float16)fmaxf(acc[r], 0.f);
    }
    __syncthreads();
    // Crow[:,0:128] = h + t @ ws2 + bs2   (B from global)
    {
        float b0 = bs2[w*16 + n];
        v4f acc = (v4f){b0, b0, b0, b0};
        const __half* wp = ws2T + (size_t)(w*16 + n)*128 + quad*8;
        #pragma unroll
        for (int ks = 0; ks < 4; ks++) {
            v8h a  = *(const v8h*)&Ts[n*136 + ks*32 + quad*8];
            v8h bf = *(const v8h*)(wp + ks*32);
            acc = __builtin_amdgcn_mfma_f32_16x16x32_f16(a, bf, acc, 0, 0, 0);
        }
        #pragma unroll
        for (int r = 0; r < 4; r++) {
            int rr = quad*4 + r, col = w*16 + n;
            Crow[rr*260 + col] = Hrow[rr*132 + col] + acc[r];
        }
    }
    __syncthreads();
    // LN(256) -> Xa (2 rows per wave)
    #pragma unroll
    for (int rr = 0; rr < 2; rr++) {
        int r = w*2 + rr;
        float4 v = *(const float4*)&Crow[r*260 + 4*lane];
        float mu = waveAllSum(v.x + v.y + v.z + v.w) * (1.f/256.f);
        float d0 = v.x-mu, d1 = v.y-mu, d2 = v.z-mu, d3 = v.w-mu;
        float var = waveAllSum(d0*d0 + d1*d1 + d2*d2 + d3*d3) * (1.f/256.f);
        float rs = rsqrtf(var + EPSLN);
        float4 gv = *(const float4*)&g[4*lane];
        float4 bv = *(const float4*)&bb[4*lane];
        *(__half2*)&Xa[r*264 + 4*lane]     = __floats2half2_rn(d0*rs*gv.x + bv.x, d1*rs*gv.y + bv.y);
        *(__half2*)&Xa[r*264 + 4*lane + 2] = __floats2half2_rn(d2*rs*gv.z + bv.z, d3*rs*gv.w + bv.w);
    }
    __syncthreads();
    // u = relu(Xa @ wu1 + bu1)   (B from global, 8 ks, partial unroll)
    {
        float b0 = bu1[w*16 + n];
        v4f acc = (v4f){b0, b0, b0, b0};
        const __half* wp = wu1T + (size_t)(w*16 + n)*256 + quad*8;
        const _Float16* xp = &Xa[n*264 + quad*8];
        #pragma unroll 4
        for (int ks = 0; ks < 8; ks++) {
            v8h a  = *(const v8h*)(xp + ks*32);
            v8h bf = *(const v8h*)(wp + ks*32);
            acc = __builtin_amdgcn_mfma_f32_16x16x32_f16(a, bf, acc, 0, 0, 0);
        }
        #pragma unroll
        for (int r = 0; r < 4; r++)
            Ut[(quad*4 + r)*136 + w*16 + n] = (_Float16)fmaxf(acc[r], 0.f);
    }
    __syncthreads();
    // hout = h + u @ wu2 + bu2   (B from global)
    {
        float b0 = bu2[w*16 + n];
        v4f acc = (v4f){b0, b0, b0, b0};
        const __half* wp = wu2T + (size_t)(w*16 + n)*128 + quad*8;
        #pragma unroll
        for (int ks = 0; ks < 4; ks++) {
            v8h a  = *(const v8h*)&Ut[n*136 + ks*32 + quad*8];
            v8h bf = *(const v8h*)(wp + ks*32);
            acc = __builtin_amdgcn_mfma_f32_16x16x32_f16(a, bf, acc, 0, 0, 0);
        }
        #pragma unroll
        for (int r = 0; r < 4; r++) {
            int rr = quad*4 + r, col = w*16 + n;
            hout[(size_t)(row0 + rr)*128 + col] = Hrow[rr*132 + col] + acc[r];
        }
    }
}

// ---------- launch ----------
extern "C" void kernel_launch(void* const* d_in, const int* in_sizes, int n_in,
                              void* d_out, int out_size, void* d_ws, size_t ws_size,
                              hipStream_t stream) {
    const float* slots = (const float*)d_in[0];
    const float* ep    = (const float*)d_in[1];
    const float* et    = (const float*)d_in[2];
    const float* ls_g  = (const float*)d_in[3];
    const float* ls_b  = (const float*)d_in[4];
    const float* ws1   = (const float*)d_in[5];
    const float* bs1   = (const float*)d_in[6];
    const float* ws2   = (const float*)d_in[7];
    const float* bs2   = (const float*)d_in[8];
    const float* wi1   = (const float*)d_in[9];
    const float* bi1   = (const float*)d_in[10];
    const float* wi2   = (const float*)d_in[11];
    const float* bi2   = (const float*)d_in[12];
    const float* wi3   = (const float*)d_in[13];
    const float* bi3   = (const float*)d_in[14];
    const float* lu_g  = (const float*)d_in[15];
    const float* lu_b  = (const float*)d_in[16];
    const float* wu1   = (const float*)d_in[17];
    const float* bu1   = (const float*)d_in[18];
    const float* wu2   = (const float*)d_in[19];
    const float* bu2   = (const float*)d_in[20];
    float* out = (float*)d_out;

    char* p = (char*)d_ws;
    float*  h_buf   = (float*)p;   p += (size_t)NSLOT*DDIM*4;
    __half* Ycat    = (__half*)p;  p += (size_t)NSLOT*YROW*2;
    __half* wPre    = (__half*)p;  p += (size_t)TTYPE*BATCH*4096*2;
    __half* ws1T    = (__half*)p;  p += 128*128*2;
    __half* wi1catT = (__half*)p;  p += 1024*128*2;
    __half* ws2T    = (__half*)p;  p += 128*128*2;
    __half* wu1T    = (__half*)p;  p += 128*256*2;
    __half* wu2T    = (__half*)p;  p += 128*128*2;
    __half* w3catT  = (__half*)p;  p += 128*YROW*2;
    __half* w2T16   = (__half*)p;  p += 4*128*128*2;
    float*  biascat = (float*)p;   p += 1024*4;

    k_wconv<<<22 + 256, 256, 0, stream>>>(ws1, wi1, ws2, wu1, wu2, wi3, wi2, bi1, bi3,
                                          ep, et, ws1T, wi1catT, ws2T, wu1T, wu2T,
                                          w3catT, w2T16, biascat, wPre);

    for (int mp = 0; mp < 2; mp++) {
        const float* h = (mp == 0) ? slots : h_buf;
        float* hout = (mp == 0) ? h_buf : out;
        k_pair<<<BATCH*TTYPE, 512, 0, stream>>>(h, wi1catT, biascat, w2T16, bi2, wPre, Ycat);
        k_mega<<<NSLOT/16, 512, 0, stream>>>(Ycat, w3catT, ls_g, ls_b, ws1T, bs1, ws2T, bs2,
                                             lu_g, lu_b, wu1T, bu1, wu2T, bu2, h, hout);
    }
}